// Round 5
// baseline (293.397 us; speedup 1.0000x reference)
//
#include <hip/hip_runtime.h>
#include <hip/hip_bf16.h>

#define BATCH 8192
#define NLAY  60
#define ROWS  32      // 2 independent 16-row groups per block, dual-chain ILP
#define TPB   256
#define SX    136     // xh row stride (ushort)
#define SM    968     // memAll row stride (ushort)
#define SI    244     // inm row stride (float)
#define LOG2E 1.44269504089f
#define T2L   2.88539008178f

typedef unsigned short ushort_t;
typedef __attribute__((ext_vector_type(8))) short short8;
typedef __attribute__((ext_vector_type(4))) float f32x4;
typedef __attribute__((ext_vector_type(4))) float f4v;

__device__ __forceinline__ float rcp_(float x) { return __builtin_amdgcn_rcpf(x); }
__device__ __forceinline__ float ex2_(float x) { return __builtin_amdgcn_exp2f(x); }
__device__ __forceinline__ ushort_t f2bu(float f) {
  unsigned u = __float_as_uint(f);
  return (ushort_t)((u + 0x7FFFu + ((u >> 16) & 1u)) >> 16);
}
__device__ __forceinline__ unsigned pkbf(float a, float b) {
  union { __hip_bfloat162 h; unsigned u; } c;
  c.h = __float22bfloat162_rn(make_float2(a, b));
  return c.u;
}
__device__ __forceinline__ f32x4 mfma16(short8 a, short8 b, f32x4 c) {
  return __builtin_amdgcn_mfma_f32_16x16x32_bf16(a, b, c, 0, 0, 0);
}
// LDS-only barrier (global stores stay in flight; full __syncthreads only at
// the LSTM1->LSTM2 transition where the block re-reads its own r1 stores).
#define BAR() asm volatile("s_waitcnt lgkmcnt(0)\n\ts_barrier" ::: "memory")

// ---- Pre-pass: pack weights into MFMA B-fragment order (bf16 bits) ----
// LSTM1 K-order: [x 0..63 | h 64..127 | mem 128..143 | pad 144..159]
// Gate weights PRE-SCALED: i,f,o by log2e ; g by 2*log2e (exp2-domain epilogue).
// W1f [w][g][ks5][512] @0 ; W2f [w][g][ks4][512] @40960 ; WlF @73728 ;
// WcF (Wo@Wl) @74752 ; WsF (Wso) @75776. Total 76800 ushorts.
__global__ void wtranspose(const float* __restrict__ Wih1, const float* __restrict__ Whh1,
                           const float* __restrict__ Wih2, const float* __restrict__ Whh2,
                           const float* __restrict__ Wl,   const float* __restrict__ Wo,
                           const float* __restrict__ Wso,  ushort_t* __restrict__ frag) {
  int e = blockIdx.x * 256 + threadIdx.x;
  float v;
  if (e < 40960) {
    int j = e & 7, lx = (e >> 3) & 63, rest = e >> 9;
    int ks = rest % 5, gw = rest / 5;
    int g = gw & 3, wv = gw >> 2;
    int row = g * 64 + wv * 16 + (lx & 15);
    int k = ks * 32 + (lx >> 4) * 8 + j;
    v = (k < 64)  ? Wih1[row * 80 + k]
      : (k < 128) ? Whh1[row * 64 + (k - 64)]
      : (k < 144) ? Wih1[row * 80 + 64 + (k - 128)]
      : 0.0f;
    v *= (g == 2) ? T2L : LOG2E;
  } else if (e < 73728) {
    int e2 = e - 40960;
    int j = e2 & 7, lx = (e2 >> 3) & 63, rest = e2 >> 9;
    int ks = rest & 3, g = (rest >> 2) & 3, wv = rest >> 4;
    int row = g * 64 + wv * 16 + (lx & 15);
    int k = ks * 32 + (lx >> 4) * 8 + j;
    v = (k < 64) ? Wih2[row * 64 + k] : Whh2[row * 64 + (k - 64)];
    v *= (g == 2) ? T2L : LOG2E;
  } else if (e < 74752) {
    int e3 = e - 73728;
    int j = e3 & 7, lx = (e3 >> 3) & 63, ks = e3 >> 9;
    int n = lx & 15, k = ks * 32 + (lx >> 4) * 8 + j;
    v = Wl[n * 64 + k];
  } else if (e < 75776) {
    int e4 = e - 74752;
    int j = e4 & 7, lx = (e4 >> 3) & 63, ks = e4 >> 9;
    int n = lx & 15, k = ks * 32 + (lx >> 4) * 8 + j;
    v = 0.0f;
    if (n < 4) {
#pragma unroll
      for (int m = 0; m < 16; ++m) v += Wo[n * 16 + m] * Wl[m * 64 + k];
    }
  } else {
    int e5 = e - 75776;
    int j = e5 & 7, lx = (e5 >> 3) & 63, ks = e5 >> 9;
    int n = lx & 15, k = ks * 32 + (lx >> 4) * 8 + j;
    v = (n < 3) ? Wso[n * 64 + k] : 0.0f;
  }
  frag[e] = f2bu(v);
}

// ---- Fused LSTM: 256 blocks x 256 thr, 32 rows/block as TWO independent
// 16-row groups per wave (dual dependency chains interleaved in-wave).
// Weights B1f/B2f shared across groups (paid once in VGPRs); one barrier
// per step serves both groups. 1 block/CU by design: concurrency moved
// from wave-level (2 coupled waves/SIMD @ 50% VALUBusy, rounds 0-4) to
// instruction-level ILP inside each wave. ----
__global__ __launch_bounds__(TPB, 1)
void lstm_fused(const float* __restrict__ inputs_main, const float* __restrict__ inputs_aux,
                const float* __restrict__ rnn1_mem,
                const float* __restrict__ Wi,  const float* __restrict__ bi,
                const float* __restrict__ Ws1, const float* __restrict__ bs1,
                const float* __restrict__ Ws2, const float* __restrict__ bs2,
                const float* __restrict__ Wt1, const float* __restrict__ bt1,
                const float* __restrict__ Wt2, const float* __restrict__ bt2,
                const float* __restrict__ bih1, const float* __restrict__ bhh1,
                const float* __restrict__ bih2, const float* __restrict__ bhh2,
                const float* __restrict__ bl,  const float* __restrict__ Wo,
                const float* __restrict__ bo,  const float* __restrict__ bso,
                const ushort_t* __restrict__ frag,
                ushort_t* __restrict__ r1buf,
                float* __restrict__ out, float* __restrict__ out_sfc,
                float* __restrict__ new_mem) {
  const ushort_t* W1f = frag;
  const ushort_t* W2f = frag + 40960;
  const ushort_t* WlF = frag + 73728;
  const ushort_t* WcF = frag + 74752;
  const ushort_t* WsF = frag + 75776;

  __shared__ __align__(16) ushort_t xh[2][2][16 * SX];   // [group][buf]
  __shared__ __align__(16) ushort_t memAll[2][16 * SM];  // [group][row][t*16+m]
  __shared__ __align__(16) float    inm[2][16 * SI];     // [group][row][t*4+c]

  const int tid = threadIdx.x;
  const int lane = tid & 63, w = tid >> 6;
  const int ln = lane & 15, lq = lane >> 4;
  const int u = w * 16 + ln;
  const int rowbase = lq * 4;
  const int b0 = blockIdx.x * ROWS;
  const int xr = tid >> 4, xc0 = (tid & 15) * 4;     // x-gen: row, 4 channels
  const int gsel = tid >> 7, tl = tid & 127;         // LSTM2 r1 stage: half-block/group
  const int rr8 = tl >> 3, ch8 = tl & 7;

  ushort_t* r1blk = r1buf + (size_t)blockIdx.x * (60 * 32 * 64);

  // B1 fragments (prescaled weights) — shared by both groups
  short8 B1f[4][5];
#pragma unroll
  for (int g = 0; g < 4; ++g)
#pragma unroll
    for (int ks = 0; ks < 5; ++ks)
      B1f[g][ks] = *(const short8*)(W1f + (((w * 4 + g) * 5 + ks) << 9) + (lane << 3));
  float bg1[4];
#pragma unroll
  for (int g = 0; g < 4; ++g)
    bg1[g] = (bih1[g * 64 + u] + bhh1[g * 64 + u]) * ((g == 2) ? T2L : LOG2E);

  // x-generator weights, prescaled by 2*log2e
  f4v wif[4];
#pragma unroll
  for (int cc = 0; cc < 4; ++cc) wif[cc] = *(const f4v*)(Wi + (xc0 + cc) * 4) * T2L;
  f4v bifv = *(const f4v*)(bi + xc0) * T2L;

  // ---- stage static inputs (both groups) ----
  for (int e = tid; e < 32 * 240; e += TPB) {
    int r = e / 240, c = e - r * 240;
    inm[r >> 4][(r & 15) * SI + c] = inputs_main[(size_t)(b0 + r) * 240 + c];
  }
  for (int e = tid; e < 32 * 960; e += TPB) {
    int r = e / 960, c = e - r * 960;
    memAll[r >> 4][(r & 15) * SM + c] = f2bu(rnn1_mem[(size_t)(b0 + r) * 960 + c]);
  }
  __syncthreads();

  // ---- prologue: x(59) + h1/c1 init into buffer 0 (both groups) ----
  float ct1[2][4];   // cell state in 2*log2e-scaled domain
  {
#pragma unroll
    for (int G = 0; G < 2; ++G) {
      f4v xin = *(const f4v*)&inm[G][xr * SI + 59 * 4];
      float xp[4];
#pragma unroll
      for (int cc = 0; cc < 4; ++cc) {
        float a = fmaf(wif[cc][3], xin[3], fmaf(wif[cc][2], xin[2],
                  fmaf(wif[cc][1], xin[1], fmaf(wif[cc][0], xin[0], bifv[cc]))));
        xp[cc] = fmaf(rcp_(1.0f + ex2_(a)), -2.0f, 1.0f);
      }
      *(uint2*)&xh[G][0][xr * SX + xc0] = make_uint2(pkbf(xp[0], xp[1]), pkbf(xp[2], xp[3]));
    }
    float w10 = Ws1[u * 3 + 0] * T2L, w11 = Ws1[u * 3 + 1] * T2L, w12 = Ws1[u * 3 + 2] * T2L;
    float bb1 = bs1[u] * T2L;
    float w20 = Ws2[u * 3 + 0] * T2L, w21 = Ws2[u * 3 + 1] * T2L, w22 = Ws2[u * 3 + 2] * T2L;
    float bb2 = bs2[u] * T2L;
#pragma unroll
    for (int G = 0; G < 2; ++G)
#pragma unroll
      for (int reg = 0; reg < 4; ++reg) {
        int row = rowbase + reg;
        const float* ax = inputs_aux + (size_t)(b0 + G * 16 + row) * 3;
        float a0 = ax[0], a1 = ax[1], a2 = ax[2];
        float ha = w10 * a0 + w11 * a1 + w12 * a2 + bb1;
        xh[G][0][row * SX + 64 + u] = f2bu(fmaf(rcp_(1.0f + ex2_(ha)), -2.0f, 1.0f));
        float ca = w20 * a0 + w21 * a1 + w22 * a2 + bb2;
        ct1[G][reg] = fmaf(rcp_(1.0f + ex2_(ca)), -2.0f * T2L, T2L);
      }
  }
  __syncthreads();

  unsigned sxv[2][4], syv[2][4];
  int pb = 0;

  // ---- LSTM1: t = 59..0 in groups of 4; r1 flushed once per group ----
  for (int tg = 14; tg >= 0; --tg) {
#pragma unroll
    for (int s = 3; s >= 0; --s) {
      const int t = tg * 4 + s;
      const int nb = pb ^ 1;
      short8 af[2][5];
#pragma unroll
      for (int G = 0; G < 2; ++G) {
        const ushort_t* xrow = &xh[G][pb][ln * SX];
        af[G][0] = *(const short8*)(xrow + lq * 8);
        af[G][1] = *(const short8*)(xrow + 32 + lq * 8);
        af[G][2] = *(const short8*)(xrow + 64 + lq * 8);
        af[G][3] = *(const short8*)(xrow + 96 + lq * 8);
        af[G][4] = (short8){};
        if (lq < 2) af[G][4] = *(const short8*)(memAll[G] + ln * SM + t * 16 + lq * 8);
      }

      f32x4 acc[2][4];
#pragma unroll
      for (int G = 0; G < 2; ++G)
#pragma unroll
        for (int g = 0; g < 4; ++g) acc[G][g] = (f32x4){bg1[g], bg1[g], bg1[g], bg1[g]};
      __builtin_amdgcn_s_setprio(1);
#pragma unroll
      for (int g = 0; g < 4; ++g)
#pragma unroll
        for (int G = 0; G < 2; ++G) {
          acc[G][g] = mfma16(af[G][0], B1f[g][0], acc[G][g]);
          acc[G][g] = mfma16(af[G][1], B1f[g][1], acc[G][g]);
          acc[G][g] = mfma16(af[G][2], B1f[g][2], acc[G][g]);
          acc[G][g] = mfma16(af[G][3], B1f[g][3], acc[G][g]);
          acc[G][g] = mfma16(af[G][4], B1f[g][4], acc[G][g]);
        }
      __builtin_amdgcn_s_setprio(0);

      if (t > 0) {  // x(t-1) into next buffer, both groups
#pragma unroll
        for (int G = 0; G < 2; ++G) {
          f4v xin = *(const f4v*)&inm[G][xr * SI + (t - 1) * 4];
          float xp[4];
#pragma unroll
          for (int cc = 0; cc < 4; ++cc) {
            float a = fmaf(wif[cc][3], xin[3], fmaf(wif[cc][2], xin[2],
                      fmaf(wif[cc][1], xin[1], fmaf(wif[cc][0], xin[0], bifv[cc]))));
            xp[cc] = fmaf(rcp_(1.0f + ex2_(a)), -2.0f, 1.0f);
          }
          *(uint2*)&xh[G][nb][xr * SX + xc0] =
              make_uint2(pkbf(xp[0], xp[1]), pkbf(xp[2], xp[3]));
        }
      }

#pragma unroll
      for (int G = 0; G < 2; ++G) {
        float h[4];
#pragma unroll
        for (int reg = 0; reg < 4; ++reg) {
          float si = rcp_(1.0f + ex2_(-acc[G][0][reg]));
          float sf = rcp_(1.0f + ex2_(-acc[G][1][reg]));
          float so = rcp_(1.0f + ex2_(-acc[G][3][reg]));
          float gt = fmaf(rcp_(1.0f + ex2_(acc[G][2][reg])), -2.0f * T2L, T2L);
          ct1[G][reg] = fmaf(sf, ct1[G][reg], si * gt);
          float tc = fmaf(rcp_(1.0f + ex2_(ct1[G][reg])), -2.0f, 1.0f);
          h[reg] = so * tc;
        }
        unsigned h01 = pkbf(h[0], h[1]), h23 = pkbf(h[2], h[3]);
        sxv[G][s] = h01; syv[G][s] = h23;      // stash; flush after the group
        if (t > 0) {
          xh[G][nb][(rowbase + 0) * SX + 64 + u] = (ushort_t)h01;
          xh[G][nb][(rowbase + 1) * SX + 64 + u] = (ushort_t)(h01 >> 16);
          xh[G][nb][(rowbase + 2) * SX + 64 + u] = (ushort_t)h23;
          xh[G][nb][(rowbase + 3) * SX + 64 + u] = (ushort_t)(h23 >> 16);
        } else {                                // r1(0) seeds LSTM2 input region
          xh[G][nb][(rowbase + 0) * SX + u] = (ushort_t)h01;
          xh[G][nb][(rowbase + 1) * SX + u] = (ushort_t)(h01 >> 16);
          xh[G][nb][(rowbase + 2) * SX + u] = (ushort_t)h23;
          xh[G][nb][(rowbase + 3) * SX + u] = (ushort_t)(h23 >> 16);
        }
      }
      BAR();
      pb = nb;
    }
    // flush r1 for tt = tg*4 .. tg*4+3 (retires in background)
#pragma unroll
    for (int G = 0; G < 2; ++G) {
      ushort_t* rp = r1blk + G * 61440 + (tg << 12) + rowbase * 64 + u;
#pragma unroll
      for (int s = 0; s < 4; ++s) {
        unsigned a = sxv[G][s], b = syv[G][s];
        rp[s * 1024 + 0 * 64] = (ushort_t)a;
        rp[s * 1024 + 1 * 64] = (ushort_t)(a >> 16);
        rp[s * 1024 + 2 * 64] = (ushort_t)b;
        rp[s * 1024 + 3 * 64] = (ushort_t)(b >> 16);
      }
    }
  }

  // ---- LSTM2 setup ----
  short8 B2f[4][4];
#pragma unroll
  for (int g = 0; g < 4; ++g)
#pragma unroll
    for (int ks = 0; ks < 4; ++ks)
      B2f[g][ks] = *(const short8*)(W2f + (((w * 4 + g) * 4 + ks) << 9) + (lane << 3));
  float bg2[4];
#pragma unroll
  for (int g = 0; g < 4; ++g)
    bg2[g] = (bih2[g * 64 + u] + bhh2[g * 64 + u]) * ((g == 2) ? T2L : LOG2E);

  float ct2[2][4];
  {
    float wt1u = Wt1[u], wt2u = Wt2[u], bt1u = bt1[u], bt2u = bt2[u];
#pragma unroll
    for (int G = 0; G < 2; ++G)
#pragma unroll
      for (int reg = 0; reg < 4; ++reg) {
        int row = rowbase + reg;
        float toa = inputs_aux[(size_t)(b0 + G * 16 + row) * 3 + 1];
        xh[G][pb][row * SX + 64 + u] = f2bu(toa * wt1u + bt1u);   // no tanh (ref)
        ct2[G][reg] = (toa * wt2u + bt2u) * T2L;
      }
  }
  short8 PW0 = {}, PW1 = {};
  float pbias = 0.0f;
  if (w == 0) {
    PW0 = *(const short8*)(WlF + (lane << 3));
    PW1 = *(const short8*)(WlF + 512 + (lane << 3));
    pbias = bl[ln];
  } else if (w == 1) {
    PW0 = *(const short8*)(WcF + (lane << 3));
    PW1 = *(const short8*)(WcF + 512 + (lane << 3));
    if (ln < 4) {
      float a = bo[ln];
#pragma unroll
      for (int m = 0; m < 16; ++m) a += Wo[ln * 16 + m] * bl[m];
      pbias = a;
    }
  } else if (w == 2) {
    PW0 = *(const short8*)(WsF + (lane << 3));
    PW1 = *(const short8*)(WsF + 512 + (lane << 3));
    pbias = (ln < 3) ? bso[ln] : 0.0f;
  }
  // r1 re-stage: threads 0..127 -> group 0, 128..255 -> group 1
  const ushort_t* r1rp = r1blk + gsel * 61440 + 1024 + rr8 * 64 + ch8 * 8;
  float* nmb[2];  float* outb[2];
#pragma unroll
  for (int G = 0; G < 2; ++G) {
    nmb[G]  = new_mem + (size_t)(b0 + G * 16 + rowbase) * 960 + ln;
    outb[G] = out + (size_t)(b0 + G * 16 + rowbase) * 240 + ln;
  }
  f32x4 pst[2][4];
  __syncthreads();   // FULL barrier: drains r1 global writes before re-reads

  // ---- LSTM2: t = 0..59 in groups of 4; proj stores flushed per group ----
  for (int tg = 0; tg < 15; ++tg) {
#pragma unroll
    for (int s = 0; s < 4; ++s) {
      const int t = tg * 4 + s;
      const int nb = pb ^ 1;
      short8 r1v = {};
      if (t < 59) r1v = *(const short8*)(r1rp + t * 1024);

      short8 af[2][4];
#pragma unroll
      for (int G = 0; G < 2; ++G) {
        const ushort_t* xrow = &xh[G][pb][ln * SX];
        af[G][0] = *(const short8*)(xrow + lq * 8);
        af[G][1] = *(const short8*)(xrow + 32 + lq * 8);
        af[G][2] = *(const short8*)(xrow + 64 + lq * 8);
        af[G][3] = *(const short8*)(xrow + 96 + lq * 8);
      }

      f32x4 acc[2][4];
#pragma unroll
      for (int G = 0; G < 2; ++G)
#pragma unroll
        for (int g = 0; g < 4; ++g) acc[G][g] = (f32x4){bg2[g], bg2[g], bg2[g], bg2[g]};
      __builtin_amdgcn_s_setprio(1);
#pragma unroll
      for (int g = 0; g < 4; ++g)
#pragma unroll
        for (int G = 0; G < 2; ++G) {
          acc[G][g] = mfma16(af[G][0], B2f[g][0], acc[G][g]);
          acc[G][g] = mfma16(af[G][1], B2f[g][1], acc[G][g]);
          acc[G][g] = mfma16(af[G][2], B2f[g][2], acc[G][g]);
          acc[G][g] = mfma16(af[G][3], B2f[g][3], acc[G][g]);
        }
      if (t > 0 && w < 2) {  // projection of h2(t-1) — reuses af2/af3
#pragma unroll
        for (int G = 0; G < 2; ++G) {
          f32x4 ap = (f32x4){pbias, pbias, pbias, pbias};
          ap = mfma16(af[G][2], PW0, ap);
          ap = mfma16(af[G][3], PW1, ap);
          pst[G][(t - 1) & 3] = ap;
        }
      }
      __builtin_amdgcn_s_setprio(0);

#pragma unroll
      for (int G = 0; G < 2; ++G) {
        float h[4];
#pragma unroll
        for (int reg = 0; reg < 4; ++reg) {
          float si = rcp_(1.0f + ex2_(-acc[G][0][reg]));
          float sf = rcp_(1.0f + ex2_(-acc[G][1][reg]));
          float so = rcp_(1.0f + ex2_(-acc[G][3][reg]));
          float gt = fmaf(rcp_(1.0f + ex2_(acc[G][2][reg])), -2.0f * T2L, T2L);
          ct2[G][reg] = fmaf(sf, ct2[G][reg], si * gt);
          float tc = fmaf(rcp_(1.0f + ex2_(ct2[G][reg])), -2.0f, 1.0f);
          h[reg] = so * tc;
        }
        unsigned h01 = pkbf(h[0], h[1]), h23 = pkbf(h[2], h[3]);
        xh[G][nb][(rowbase + 0) * SX + 64 + u] = (ushort_t)h01;
        xh[G][nb][(rowbase + 1) * SX + 64 + u] = (ushort_t)(h01 >> 16);
        xh[G][nb][(rowbase + 2) * SX + 64 + u] = (ushort_t)h23;
        xh[G][nb][(rowbase + 3) * SX + 64 + u] = (ushort_t)(h23 >> 16);
      }
      if (t < 59) *(short8*)&xh[gsel][nb][rr8 * SX + ch8 * 8] = r1v;
      BAR();
      pb = nb;
    }
    // flush projections: slots 0,1,2 -> pt = tg*4+{0,1,2}; slot 3 -> pt = tg*4-1
    if (w < 2) {
      const int base = tg * 4;
#pragma unroll
      for (int G = 0; G < 2; ++G)
#pragma unroll
        for (int k = 0; k < 4; ++k) {
          const int pt = (k == 3) ? base - 1 : base + k;
          if (pt < 0) continue;
          f32x4 ap = pst[G][k];
          if (w == 0) {
#pragma unroll
            for (int reg = 0; reg < 4; ++reg) nmb[G][reg * 960 + pt * 16] = ap[reg];
          } else if (ln < 4) {
#pragma unroll
            for (int reg = 0; reg < 4; ++reg) outb[G][reg * 240 + pt * 4] = ap[reg];
          }
        }
    }
  }

  // ---- tail: pt = 59 projections + out_sfc from final h2 (xh[G][pb]) ----
  if (w < 3) {
#pragma unroll
    for (int G = 0; G < 2; ++G) {
      const ushort_t* xrow = &xh[G][pb][ln * SX];
      short8 aL0 = *(const short8*)(xrow + 64 + lq * 8);
      short8 aL1 = *(const short8*)(xrow + 96 + lq * 8);
      f32x4 ap = (f32x4){pbias, pbias, pbias, pbias};
      ap = mfma16(aL0, PW0, ap);
      ap = mfma16(aL1, PW1, ap);
      if (w == 0) {
#pragma unroll
        for (int reg = 0; reg < 4; ++reg) nmb[G][reg * 960 + 59 * 16] = ap[reg];
      } else if (w == 1) {
        if (ln < 4) {
#pragma unroll
          for (int reg = 0; reg < 4; ++reg) outb[G][reg * 240 + 59 * 4] = ap[reg];
        }
      } else {
        if (ln < 3) {
#pragma unroll
          for (int reg = 0; reg < 4; ++reg)
            out_sfc[(size_t)(b0 + G * 16 + rowbase + reg) * 3 + ln] = ap[reg];
        }
      }
    }
  }
}

extern "C" void kernel_launch(void* const* d_in, const int* in_sizes, int n_in,
                              void* d_out, int out_size, void* d_ws, size_t ws_size,
                              hipStream_t stream) {
  (void)in_sizes; (void)n_in; (void)out_size; (void)ws_size;
  const float* inputs_main = (const float*)d_in[0];
  const float* inputs_aux  = (const float*)d_in[1];
  const float* rnn1_mem    = (const float*)d_in[2];
  const float* Wi   = (const float*)d_in[3];
  const float* bi   = (const float*)d_in[4];
  const float* Ws1  = (const float*)d_in[5];
  const float* bs1  = (const float*)d_in[6];
  const float* Ws2  = (const float*)d_in[7];
  const float* bs2  = (const float*)d_in[8];
  const float* Wt1  = (const float*)d_in[9];
  const float* bt1  = (const float*)d_in[10];
  const float* Wt2  = (const float*)d_in[11];
  const float* bt2  = (const float*)d_in[12];
  const float* Wih1 = (const float*)d_in[13];
  const float* Whh1 = (const float*)d_in[14];
  const float* bih1 = (const float*)d_in[15];
  const float* bhh1 = (const float*)d_in[16];
  const float* Wih2 = (const float*)d_in[17];
  const float* Whh2 = (const float*)d_in[18];
  const float* bih2 = (const float*)d_in[19];
  const float* bhh2 = (const float*)d_in[20];
  const float* Wl   = (const float*)d_in[21];
  const float* bl   = (const float*)d_in[22];
  const float* Wo   = (const float*)d_in[23];
  const float* bo   = (const float*)d_in[24];
  const float* Wso  = (const float*)d_in[25];
  const float* bso  = (const float*)d_in[26];

  float* out     = (float*)d_out;
  float* out_sfc = out + (size_t)BATCH * NLAY * 4;
  float* new_mem = out_sfc + (size_t)BATCH * 3;

  ushort_t* frag  = (ushort_t*)d_ws;                          // 76800 ushorts
  ushort_t* r1buf = (ushort_t*)((char*)d_ws + 153600);        // [block][2][60][16][64] bf16

  wtranspose<<<300, 256, 0, stream>>>(Wih1, Whh1, Wih2, Whh2, Wl, Wo, Wso, frag);
  lstm_fused<<<BATCH / ROWS, TPB, 0, stream>>>(
      inputs_main, inputs_aux, rnn1_mem, Wi, bi, Ws1, bs1, Ws2, bs2,
      Wt1, bt1, Wt2, bt2, bih1, bhh1, bih2, bhh2, bl, Wo, bo, bso,
      frag, r1buf, out, out_sfc, new_mem);
}

// Round 7
// 289.468 us; speedup vs baseline: 1.0136x; 1.0136x over previous
//
#include <hip/hip_runtime.h>
#include <hip/hip_bf16.h>

#define BATCH 8192
#define NLAY  60
#define ROWS  16
#define TPB   256
#define SX    136     // xh row stride (ushort)
#define SM    968     // memAll row stride (ushort)
#define LOG2E 1.44269504089f
#define T2L   2.88539008178f

typedef unsigned short ushort_t;
typedef __attribute__((ext_vector_type(8))) short short8;
typedef __attribute__((ext_vector_type(4))) float f32x4;
typedef __attribute__((ext_vector_type(4))) float f4v;

__device__ __forceinline__ float rcp_(float x) { return __builtin_amdgcn_rcpf(x); }
__device__ __forceinline__ float ex2_(float x) { return __builtin_amdgcn_exp2f(x); }
__device__ __forceinline__ ushort_t f2bu(float f) {
  unsigned u = __float_as_uint(f);
  return (ushort_t)((u + 0x7FFFu + ((u >> 16) & 1u)) >> 16);
}
__device__ __forceinline__ unsigned pkbf(float a, float b) {
  union { __hip_bfloat162 h; unsigned u; } c;
  c.h = __float22bfloat162_rn(make_float2(a, b));
  return c.u;
}
__device__ __forceinline__ f32x4 mfma16(short8 a, short8 b, f32x4 c) {
  return __builtin_amdgcn_mfma_f32_16x16x32_bf16(a, b, c, 0, 0, 0);
}
// LDS-only barrier (global stores stay in flight; full __syncthreads only at
// the LSTM1->LSTM2 transition where the block re-reads its own r1 stores).
#define BAR() asm volatile("s_waitcnt lgkmcnt(0)\n\ts_barrier" ::: "memory")

// ---- Pre-pass 1: pack weights into MFMA B-fragment order (bf16 bits) ----
// LSTM1 K-order: [x 0..63 | h 64..127 | mem 128..143 | pad 144..159]
// Gate weights PRE-SCALED: i,f,o by log2e ; g by 2*log2e (exp2-domain epilogue).
// W1f [w][g][ks5][512] @0 ; W2f [w][g][ks4][512] @40960 ; WlF @73728 ;
// WcF (Wo@Wl) @74752 ; WsF (Wso) @75776. Total 76800 ushorts.
__global__ void wtranspose(const float* __restrict__ Wih1, const float* __restrict__ Whh1,
                           const float* __restrict__ Wih2, const float* __restrict__ Whh2,
                           const float* __restrict__ Wl,   const float* __restrict__ Wo,
                           const float* __restrict__ Wso,  ushort_t* __restrict__ frag) {
  int e = blockIdx.x * 256 + threadIdx.x;
  float v;
  if (e < 40960) {
    int j = e & 7, lx = (e >> 3) & 63, rest = e >> 9;
    int ks = rest % 5, gw = rest / 5;
    int g = gw & 3, wv = gw >> 2;
    int row = g * 64 + wv * 16 + (lx & 15);
    int k = ks * 32 + (lx >> 4) * 8 + j;
    v = (k < 64)  ? Wih1[row * 80 + k]
      : (k < 128) ? Whh1[row * 64 + (k - 64)]
      : (k < 144) ? Wih1[row * 80 + 64 + (k - 128)]
      : 0.0f;
    v *= (g == 2) ? T2L : LOG2E;
  } else if (e < 73728) {
    int e2 = e - 40960;
    int j = e2 & 7, lx = (e2 >> 3) & 63, rest = e2 >> 9;
    int ks = rest & 3, g = (rest >> 2) & 3, wv = rest >> 4;
    int row = g * 64 + wv * 16 + (lx & 15);
    int k = ks * 32 + (lx >> 4) * 8 + j;
    v = (k < 64) ? Wih2[row * 64 + k] : Whh2[row * 64 + (k - 64)];
    v *= (g == 2) ? T2L : LOG2E;
  } else if (e < 74752) {
    int e3 = e - 73728;
    int j = e3 & 7, lx = (e3 >> 3) & 63, ks = e3 >> 9;
    int n = lx & 15, k = ks * 32 + (lx >> 4) * 8 + j;
    v = Wl[n * 64 + k];
  } else if (e < 75776) {
    int e4 = e - 74752;
    int j = e4 & 7, lx = (e4 >> 3) & 63, ks = e4 >> 9;
    int n = lx & 15, k = ks * 32 + (lx >> 4) * 8 + j;
    v = 0.0f;
    if (n < 4) {
#pragma unroll
      for (int m = 0; m < 16; ++m) v += Wo[n * 16 + m] * Wl[m * 64 + k];
    }
  } else {
    int e5 = e - 75776;
    int j = e5 & 7, lx = (e5 >> 3) & 63, ks = e5 >> 9;
    int n = lx & 15, k = ks * 32 + (lx >> 4) * 8 + j;
    v = (n < 3) ? Wso[n * 64 + k] : 0.0f;
  }
  frag[e] = f2bu(v);
}

// ---- Pre-pass 2: x(b,t,c) = tanh(Wi @ inputs_main + bi), all (b,t) in
// parallel (trans pipe at ~full occupancy here vs 50% in the main loop).
// Stored INTO r1buf slot [block][t][row][ch]: LSTM1 walks t=59..0 and reads
// x[t-1] during step t, strictly BEFORE the group flush overwrites slots
// 4tg..4tg+3 with r1 — read-before-write per slot, so x and r1 time-share
// the same workspace. ----
__global__ void xgen(const float* __restrict__ inputs_main, const float* __restrict__ Wi,
                     const float* __restrict__ bi, ushort_t* __restrict__ r1buf) {
  int id = blockIdx.x * 256 + threadIdx.x;          // [0, 8192*60*16)
  int b = id / 960, rem = id - b * 960;
  int t = rem >> 4, q = rem & 15;
  f4v xin = *(const f4v*)(inputs_main + (size_t)b * 240 + t * 4);
  float xp[4];
#pragma unroll
  for (int cc = 0; cc < 4; ++cc) {
    int ch = q * 4 + cc;
    f4v wv = *(const f4v*)(Wi + ch * 4);
    float a = (wv[0] * xin[0] + wv[1] * xin[1] + wv[2] * xin[2] + wv[3] * xin[3]
               + bi[ch]) * T2L;
    xp[cc] = fmaf(rcp_(1.0f + ex2_(a)), -2.0f, 1.0f);
  }
  ushort_t* dst = r1buf + (size_t)(b >> 4) * 61440 + t * 1024 + (b & 15) * 64 + q * 4;
  *(uint2*)dst = make_uint2(pkbf(xp[0], xp[1]), pkbf(xp[2], xp[3]));
}

// ---- Fused LSTM: 512 blocks x 256 thr, 16 rows/block, 2 blocks/CU.
// Round-5 post-mortem: in-wave ILP != TLP (1 wave/SIMD exposes all latency);
// rounds 1-3: more blocks/CU impossible (zero-pad MFMA tax, 128-reg wall).
// This round: x-generator hoisted to xgen pre-pass — per-step x-gen
// (8 trans + ~20 VALU, ~18% of the VALU budget) replaced by a prefetched
// 16B load from r1buf + 16B LDS write. inm LDS dropped (55.3->39.7 KB). ----
__global__ __launch_bounds__(TPB, 2)
void lstm_fused(const float* __restrict__ inputs_aux,
                const float* __restrict__ rnn1_mem,
                const float* __restrict__ Ws1, const float* __restrict__ bs1,
                const float* __restrict__ Ws2, const float* __restrict__ bs2,
                const float* __restrict__ Wt1, const float* __restrict__ bt1,
                const float* __restrict__ Wt2, const float* __restrict__ bt2,
                const float* __restrict__ bih1, const float* __restrict__ bhh1,
                const float* __restrict__ bih2, const float* __restrict__ bhh2,
                const float* __restrict__ bl,  const float* __restrict__ Wo,
                const float* __restrict__ bo,  const float* __restrict__ bso,
                const ushort_t* __restrict__ frag,
                ushort_t* __restrict__ r1buf,
                float* __restrict__ out, float* __restrict__ out_sfc,
                float* __restrict__ new_mem) {
  const ushort_t* W1f = frag;
  const ushort_t* W2f = frag + 40960;
  const ushort_t* WlF = frag + 73728;
  const ushort_t* WcF = frag + 74752;
  const ushort_t* WsF = frag + 75776;

  __shared__ __align__(16) ushort_t xh[2][16 * SX];   // LSTM1: x|h1 ; LSTM2: r1|h2
  __shared__ __align__(16) ushort_t memAll[16 * SM];  // [row][t*16+m] bf16

  const int tid = threadIdx.x;
  const int lane = tid & 63, w = tid >> 6;
  const int ln = lane & 15, lq = lane >> 4;
  const int u = w * 16 + ln;
  const int rowbase = lq * 4;
  const int b0 = blockIdx.x * ROWS;
  const int rr8 = tid >> 3, ch8 = tid & 7;   // x prefetch (tid<128) / r1 stage

  ushort_t* r1blk = r1buf + (size_t)blockIdx.x * (60 * 16 * 64);

  // B1 fragments (prescaled weights)
  short8 B1f[4][5];
#pragma unroll
  for (int g = 0; g < 4; ++g)
#pragma unroll
    for (int ks = 0; ks < 5; ++ks)
      B1f[g][ks] = *(const short8*)(W1f + (((w * 4 + g) * 5 + ks) << 9) + (lane << 3));
  float bg1[4];
#pragma unroll
  for (int g = 0; g < 4; ++g)
    bg1[g] = (bih1[g * 64 + u] + bhh1[g * 64 + u]) * ((g == 2) ? T2L : LOG2E);

  // ---- stage static inputs; x(59) tile comes from xgen's output ----
  for (int e = tid; e < 16 * 240; e += TPB) {
    int r = e / 240, c = e - r * 240;
    f4v mv = *(const f4v*)(rnn1_mem + (size_t)(b0 + r) * 960 + c * 4);
    *(uint2*)&memAll[r * SM + c * 4] = make_uint2(pkbf(mv[0], mv[1]), pkbf(mv[2], mv[3]));
  }
  if (tid < 128) {   // x(59) -> xh[0] x-region (16 rows x 64 ch bf16)
    short8 xv = *(const short8*)(r1blk + 59 * 1024 + rr8 * 64 + ch8 * 8);
    *(short8*)&xh[0][rr8 * SX + ch8 * 8] = xv;
  }

  // ---- prologue: h1/c1 init into buffer 0 ----
  float ct1[4];   // cell state in 2*log2e-scaled domain
  {
    float w10 = Ws1[u * 3 + 0] * T2L, w11 = Ws1[u * 3 + 1] * T2L, w12 = Ws1[u * 3 + 2] * T2L;
    float bb1 = bs1[u] * T2L;
    float w20 = Ws2[u * 3 + 0] * T2L, w21 = Ws2[u * 3 + 1] * T2L, w22 = Ws2[u * 3 + 2] * T2L;
    float bb2 = bs2[u] * T2L;
#pragma unroll
    for (int reg = 0; reg < 4; ++reg) {
      int row = rowbase + reg;
      const float* ax = inputs_aux + (size_t)(b0 + row) * 3;
      float a0 = ax[0], a1 = ax[1], a2 = ax[2];
      float ha = w10 * a0 + w11 * a1 + w12 * a2 + bb1;
      xh[0][row * SX + 64 + u] = f2bu(fmaf(rcp_(1.0f + ex2_(ha)), -2.0f, 1.0f));
      float ca = w20 * a0 + w21 * a1 + w22 * a2 + bb2;
      ct1[reg] = fmaf(rcp_(1.0f + ex2_(ca)), -2.0f * T2L, T2L);
    }
  }
  __syncthreads();

  ushort_t* r1t = r1blk + rowbase * 64 + u;
  unsigned sxv[4], syv[4];
  int pb = 0;

  // ---- LSTM1: t = 59..0 in groups of 4; r1 flushed once per group ----
  for (int tg = 14; tg >= 0; --tg) {
#pragma unroll
    for (int s = 3; s >= 0; --s) {
      const int t = tg * 4 + s;
      const int nb = pb ^ 1;
      // prefetch x(t-1) from xgen output (slot not yet overwritten by r1)
      short8 xv;
      const bool lx = (t > 0) && (tid < 128);
      if (lx) xv = *(const short8*)(r1blk + (size_t)(t - 1) * 1024 + rr8 * 64 + ch8 * 8);

      const ushort_t* xrow = &xh[pb][ln * SX];
      short8 af0 = *(const short8*)(xrow + lq * 8);
      short8 af1 = *(const short8*)(xrow + 32 + lq * 8);
      short8 af2 = *(const short8*)(xrow + 64 + lq * 8);
      short8 af3 = *(const short8*)(xrow + 96 + lq * 8);
      short8 af4 = {};
      if (lq < 2) af4 = *(const short8*)(memAll + ln * SM + t * 16 + lq * 8);

      f32x4 acc[4];
#pragma unroll
      for (int g = 0; g < 4; ++g) acc[g] = (f32x4){bg1[g], bg1[g], bg1[g], bg1[g]};
      __builtin_amdgcn_s_setprio(1);
#pragma unroll
      for (int g = 0; g < 4; ++g) {
        acc[g] = mfma16(af0, B1f[g][0], acc[g]);
        acc[g] = mfma16(af1, B1f[g][1], acc[g]);
        acc[g] = mfma16(af2, B1f[g][2], acc[g]);
        acc[g] = mfma16(af3, B1f[g][3], acc[g]);
        acc[g] = mfma16(af4, B1f[g][4], acc[g]);
      }
      __builtin_amdgcn_s_setprio(0);

      float h[4];
#pragma unroll
      for (int reg = 0; reg < 4; ++reg) {
        float si = rcp_(1.0f + ex2_(-acc[0][reg]));
        float sf = rcp_(1.0f + ex2_(-acc[1][reg]));
        float so = rcp_(1.0f + ex2_(-acc[3][reg]));
        float gt = fmaf(rcp_(1.0f + ex2_(acc[2][reg])), -2.0f * T2L, T2L);
        ct1[reg] = fmaf(sf, ct1[reg], si * gt);
        float tc = fmaf(rcp_(1.0f + ex2_(ct1[reg])), -2.0f, 1.0f);
        h[reg] = so * tc;
      }
      unsigned h01 = pkbf(h[0], h[1]), h23 = pkbf(h[2], h[3]);
      sxv[s] = h01; syv[s] = h23;              // stash; flush after the group
      if (t > 0) {
        xh[nb][(rowbase + 0) * SX + 64 + u] = (ushort_t)h01;
        xh[nb][(rowbase + 1) * SX + 64 + u] = (ushort_t)(h01 >> 16);
        xh[nb][(rowbase + 2) * SX + 64 + u] = (ushort_t)h23;
        xh[nb][(rowbase + 3) * SX + 64 + u] = (ushort_t)(h23 >> 16);
      } else {                                  // r1(0) seeds LSTM2 input region
        xh[nb][(rowbase + 0) * SX + u] = (ushort_t)h01;
        xh[nb][(rowbase + 1) * SX + u] = (ushort_t)(h01 >> 16);
        xh[nb][(rowbase + 2) * SX + u] = (ushort_t)h23;
        xh[nb][(rowbase + 3) * SX + u] = (ushort_t)(h23 >> 16);
      }
      if (lx) *(short8*)&xh[nb][rr8 * SX + ch8 * 8] = xv;   // x(t-1) into next buf
      BAR();
      pb = nb;
    }
    // flush r1 for tt = tg*4 .. tg*4+3 (retires in background; no barrier drain)
    ushort_t* rp = r1t + (tg << 12);
#pragma unroll
    for (int s = 0; s < 4; ++s) {
      unsigned a = sxv[s], b = syv[s];
      rp[s * 1024 + 0 * 64] = (ushort_t)a;
      rp[s * 1024 + 1 * 64] = (ushort_t)(a >> 16);
      rp[s * 1024 + 2 * 64] = (ushort_t)b;
      rp[s * 1024 + 3 * 64] = (ushort_t)(b >> 16);
    }
  }

  // ---- LSTM2 setup ----
  short8 B2f[4][4];
#pragma unroll
  for (int g = 0; g < 4; ++g)
#pragma unroll
    for (int ks = 0; ks < 4; ++ks)
      B2f[g][ks] = *(const short8*)(W2f + (((w * 4 + g) * 4 + ks) << 9) + (lane << 3));
  float bg2[4];
#pragma unroll
  for (int g = 0; g < 4; ++g)
    bg2[g] = (bih2[g * 64 + u] + bhh2[g * 64 + u]) * ((g == 2) ? T2L : LOG2E);

  float ct2[4];
  {
    float wt1u = Wt1[u], wt2u = Wt2[u], bt1u = bt1[u], bt2u = bt2[u];
#pragma unroll
    for (int reg = 0; reg < 4; ++reg) {
      int row = rowbase + reg;
      float toa = inputs_aux[(size_t)(b0 + row) * 3 + 1];
      xh[pb][row * SX + 64 + u] = f2bu(toa * wt1u + bt1u);   // no tanh (ref)
      ct2[reg] = (toa * wt2u + bt2u) * T2L;
    }
  }
  short8 PW0 = {}, PW1 = {};
  float pbias = 0.0f;
  if (w == 0) {
    PW0 = *(const short8*)(WlF + (lane << 3));
    PW1 = *(const short8*)(WlF + 512 + (lane << 3));
    pbias = bl[ln];
  } else if (w == 1) {
    PW0 = *(const short8*)(WcF + (lane << 3));
    PW1 = *(const short8*)(WcF + 512 + (lane << 3));
    if (ln < 4) {
      float a = bo[ln];
#pragma unroll
      for (int m = 0; m < 16; ++m) a += Wo[ln * 16 + m] * bl[m];
      pbias = a;
    }
  } else if (w == 2) {
    PW0 = *(const short8*)(WsF + (lane << 3));
    PW1 = *(const short8*)(WsF + 512 + (lane << 3));
    pbias = (ln < 3) ? bso[ln] : 0.0f;
  }
  const ushort_t* r1rp = r1blk + 1024 + rr8 * 64 + ch8 * 8;
  float* nmb = new_mem + (size_t)(b0 + rowbase) * 960 + ln;
  float* outb = out + (size_t)(b0 + rowbase) * 240 + ln;
  f32x4 pst[4];
  __syncthreads();   // FULL barrier: drains r1 global writes before re-reads

  // ---- LSTM2: t = 0..59 in groups of 4; proj stores flushed per group ----
  for (int tg = 0; tg < 15; ++tg) {
#pragma unroll
    for (int s = 0; s < 4; ++s) {
      const int t = tg * 4 + s;
      const int nb = pb ^ 1;
      short8 r1v = {};
      if (t < 59 && tid < 128) r1v = *(const short8*)(r1rp + t * 1024);

      const ushort_t* xrow = &xh[pb][ln * SX];
      short8 af0 = *(const short8*)(xrow + lq * 8);
      short8 af1 = *(const short8*)(xrow + 32 + lq * 8);
      short8 af2 = *(const short8*)(xrow + 64 + lq * 8);
      short8 af3 = *(const short8*)(xrow + 96 + lq * 8);

      f32x4 acc[4];
#pragma unroll
      for (int g = 0; g < 4; ++g) acc[g] = (f32x4){bg2[g], bg2[g], bg2[g], bg2[g]};
      __builtin_amdgcn_s_setprio(1);
#pragma unroll
      for (int g = 0; g < 4; ++g) {
        acc[g] = mfma16(af0, B2f[g][0], acc[g]);
        acc[g] = mfma16(af1, B2f[g][1], acc[g]);
        acc[g] = mfma16(af2, B2f[g][2], acc[g]);
        acc[g] = mfma16(af3, B2f[g][3], acc[g]);
      }

      if (t > 0 && w < 2) {  // projection of h2(t-1) — reuses af2/af3
        f32x4 ap = (f32x4){pbias, pbias, pbias, pbias};
        ap = mfma16(af2, PW0, ap);
        ap = mfma16(af3, PW1, ap);
        pst[(t - 1) & 3] = ap;
      }
      __builtin_amdgcn_s_setprio(0);

      float h[4];
#pragma unroll
      for (int reg = 0; reg < 4; ++reg) {
        float si = rcp_(1.0f + ex2_(-acc[0][reg]));
        float sf = rcp_(1.0f + ex2_(-acc[1][reg]));
        float so = rcp_(1.0f + ex2_(-acc[3][reg]));
        float gt = fmaf(rcp_(1.0f + ex2_(acc[2][reg])), -2.0f * T2L, T2L);
        ct2[reg] = fmaf(sf, ct2[reg], si * gt);
        float tc = fmaf(rcp_(1.0f + ex2_(ct2[reg])), -2.0f, 1.0f);
        h[reg] = so * tc;
      }
      unsigned h01 = pkbf(h[0], h[1]), h23 = pkbf(h[2], h[3]);
      xh[nb][(rowbase + 0) * SX + 64 + u] = (ushort_t)h01;
      xh[nb][(rowbase + 1) * SX + 64 + u] = (ushort_t)(h01 >> 16);
      xh[nb][(rowbase + 2) * SX + 64 + u] = (ushort_t)h23;
      xh[nb][(rowbase + 3) * SX + 64 + u] = (ushort_t)(h23 >> 16);
      if (t < 59 && tid < 128)
        *(short8*)&xh[nb][rr8 * SX + ch8 * 8] = r1v;
      BAR();
      pb = nb;
    }
    // flush projections: slots 0,1,2 -> pt = tg*4+{0,1,2}; slot 3 -> pt = tg*4-1
    if (w < 2) {
      const int base = tg * 4;
#pragma unroll
      for (int k = 0; k < 4; ++k) {
        const int pt = (k == 3) ? base - 1 : base + k;
        if (pt < 0) continue;
        f32x4 ap = pst[k];
        if (w == 0) {
#pragma unroll
          for (int reg = 0; reg < 4; ++reg) nmb[reg * 960 + pt * 16] = ap[reg];
        } else if (ln < 4) {
#pragma unroll
          for (int reg = 0; reg < 4; ++reg) outb[reg * 240 + pt * 4] = ap[reg];
        }
      }
    }
  }

  // ---- tail: pt = 59 projections + out_sfc from final h2 (xh[pb]) ----
  if (w < 3) {
    const ushort_t* xrow = &xh[pb][ln * SX];
    short8 aL0 = *(const short8*)(xrow + 64 + lq * 8);
    short8 aL1 = *(const short8*)(xrow + 96 + lq * 8);
    f32x4 ap = (f32x4){pbias, pbias, pbias, pbias};
    ap = mfma16(aL0, PW0, ap);
    ap = mfma16(aL1, PW1, ap);
    if (w == 0) {
#pragma unroll
      for (int reg = 0; reg < 4; ++reg) nmb[reg * 960 + 59 * 16] = ap[reg];
    } else if (w == 1) {
      if (ln < 4) {
#pragma unroll
        for (int reg = 0; reg < 4; ++reg) outb[reg * 240 + 59 * 4] = ap[reg];
      }
    } else {
      if (ln < 3) {
#pragma unroll
        for (int reg = 0; reg < 4; ++reg)
          out_sfc[(size_t)(b0 + rowbase + reg) * 3 + ln] = ap[reg];
      }
    }
  }
}

extern "C" void kernel_launch(void* const* d_in, const int* in_sizes, int n_in,
                              void* d_out, int out_size, void* d_ws, size_t ws_size,
                              hipStream_t stream) {
  (void)in_sizes; (void)n_in; (void)out_size; (void)ws_size;
  const float* inputs_main = (const float*)d_in[0];
  const float* inputs_aux  = (const float*)d_in[1];
  const float* rnn1_mem    = (const float*)d_in[2];
  const float* Wi   = (const float*)d_in[3];
  const float* bi   = (const float*)d_in[4];
  const float* Ws1  = (const float*)d_in[5];
  const float* bs1  = (const float*)d_in[6];
  const float* Ws2  = (const float*)d_in[7];
  const float* bs2  = (const float*)d_in[8];
  const float* Wt1  = (const float*)d_in[9];
  const float* bt1  = (const float*)d_in[10];
  const float* Wt2  = (const float*)d_in[11];
  const float* bt2  = (const float*)d_in[12];
  const float* Wih1 = (const float*)d_in[13];
  const float* Whh1 = (const float*)d_in[14];
  const float* bih1 = (const float*)d_in[15];
  const float* bhh1 = (const float*)d_in[16];
  const float* Wih2 = (const float*)d_in[17];
  const float* Whh2 = (const float*)d_in[18];
  const float* bih2 = (const float*)d_in[19];
  const float* bhh2 = (const float*)d_in[20];
  const float* Wl   = (const float*)d_in[21];
  const float* bl   = (const float*)d_in[22];
  const float* Wo   = (const float*)d_in[23];
  const float* bo   = (const float*)d_in[24];
  const float* Wso  = (const float*)d_in[25];
  const float* bso  = (const float*)d_in[26];

  float* out     = (float*)d_out;
  float* out_sfc = out + (size_t)BATCH * NLAY * 4;
  float* new_mem = out_sfc + (size_t)BATCH * 3;

  ushort_t* frag  = (ushort_t*)d_ws;                          // 76800 ushorts
  ushort_t* r1buf = (ushort_t*)((char*)d_ws + 153600);        // [block][60][16][64] bf16
                                                              // (x prestage, then r1)

  wtranspose<<<300, 256, 0, stream>>>(Wih1, Whh1, Wih2, Whh2, Wl, Wo, Wso, frag);
  xgen<<<BATCH * NLAY * 16 / TPB, TPB, 0, stream>>>(inputs_main, Wi, bi, r1buf);
  lstm_fused<<<BATCH / ROWS, TPB, 0, stream>>>(
      inputs_aux, rnn1_mem, Ws1, bs1, Ws2, bs2,
      Wt1, bt1, Wt2, bt2, bih1, bhh1, bih2, bhh2, bl, Wo, bo, bso,
      frag, r1buf, out, out_sfc, new_mem);
}

// Round 8
// 270.905 us; speedup vs baseline: 1.0830x; 1.0685x over previous
//
#include <hip/hip_runtime.h>
#include <hip/hip_bf16.h>

#define BATCH 8192
#define NLAY  60
#define ROWS  16
#define TPB   256
#define SX    136     // xh row stride (ushort)
#define SM    968     // memAll row stride (ushort)
#define LOG2E 1.44269504089f
#define T2L   2.88539008178f

typedef unsigned short ushort_t;
typedef __attribute__((ext_vector_type(8))) short short8;
typedef __attribute__((ext_vector_type(4))) float f32x4;
typedef __attribute__((ext_vector_type(4))) float f4v;

__device__ __forceinline__ float rcp_(float x) { return __builtin_amdgcn_rcpf(x); }
__device__ __forceinline__ float ex2_(float x) { return __builtin_amdgcn_exp2f(x); }
__device__ __forceinline__ ushort_t f2bu(float f) {
  unsigned u = __float_as_uint(f);
  return (ushort_t)((u + 0x7FFFu + ((u >> 16) & 1u)) >> 16);
}
__device__ __forceinline__ unsigned pkbf(float a, float b) {
  union { __hip_bfloat162 h; unsigned u; } c;
  c.h = __float22bfloat162_rn(make_float2(a, b));
  return c.u;
}
__device__ __forceinline__ f32x4 mfma16(short8 a, short8 b, f32x4 c) {
  return __builtin_amdgcn_mfma_f32_16x16x32_bf16(a, b, c, 0, 0, 0);
}
// LDS-only barrier (global stores stay in flight; full __syncthreads only at
// the LSTM1->LSTM2 transition where the block re-reads its own r1 stores).
#define BAR() asm volatile("s_waitcnt lgkmcnt(0)\n\ts_barrier" ::: "memory")

// ---- Pre-pass 1: pack weights into MFMA B-fragment order (bf16 bits) ----
// LSTM1 K-order: [x 0..63 | h 64..127 | mem 128..143 | pad 144..159]
// Gate weights PRE-SCALED: i,f,o by log2e ; g by 2*log2e (exp2-domain epilogue).
// W1f [w][g][ks5][512] @0 ; W2f [w][g][ks4][512] @40960 ; WlF @73728 ;
// WcF (Wo@Wl) @74752 ; WsF (Wso) @75776. Total 76800 ushorts.
__global__ void wtranspose(const float* __restrict__ Wih1, const float* __restrict__ Whh1,
                           const float* __restrict__ Wih2, const float* __restrict__ Whh2,
                           const float* __restrict__ Wl,   const float* __restrict__ Wo,
                           const float* __restrict__ Wso,  ushort_t* __restrict__ frag) {
  int e = blockIdx.x * 256 + threadIdx.x;
  float v;
  if (e < 40960) {
    int j = e & 7, lx = (e >> 3) & 63, rest = e >> 9;
    int ks = rest % 5, gw = rest / 5;
    int g = gw & 3, wv = gw >> 2;
    int row = g * 64 + wv * 16 + (lx & 15);
    int k = ks * 32 + (lx >> 4) * 8 + j;
    v = (k < 64)  ? Wih1[row * 80 + k]
      : (k < 128) ? Whh1[row * 64 + (k - 64)]
      : (k < 144) ? Wih1[row * 80 + 64 + (k - 128)]
      : 0.0f;
    v *= (g == 2) ? T2L : LOG2E;
  } else if (e < 73728) {
    int e2 = e - 40960;
    int j = e2 & 7, lx = (e2 >> 3) & 63, rest = e2 >> 9;
    int ks = rest & 3, g = (rest >> 2) & 3, wv = rest >> 4;
    int row = g * 64 + wv * 16 + (lx & 15);
    int k = ks * 32 + (lx >> 4) * 8 + j;
    v = (k < 64) ? Wih2[row * 64 + k] : Whh2[row * 64 + (k - 64)];
    v *= (g == 2) ? T2L : LOG2E;
  } else if (e < 74752) {
    int e3 = e - 73728;
    int j = e3 & 7, lx = (e3 >> 3) & 63, ks = e3 >> 9;
    int n = lx & 15, k = ks * 32 + (lx >> 4) * 8 + j;
    v = Wl[n * 64 + k];
  } else if (e < 75776) {
    int e4 = e - 74752;
    int j = e4 & 7, lx = (e4 >> 3) & 63, ks = e4 >> 9;
    int n = lx & 15, k = ks * 32 + (lx >> 4) * 8 + j;
    v = 0.0f;
    if (n < 4) {
#pragma unroll
      for (int m = 0; m < 16; ++m) v += Wo[n * 16 + m] * Wl[m * 64 + k];
    }
  } else {
    int e5 = e - 75776;
    int j = e5 & 7, lx = (e5 >> 3) & 63, ks = e5 >> 9;
    int n = lx & 15, k = ks * 32 + (lx >> 4) * 8 + j;
    v = (n < 3) ? Wso[n * 64 + k] : 0.0f;
  }
  frag[e] = f2bu(v);
}

// ---- Pre-pass 2: x(b,t,c) = tanh(Wi @ inputs_main + bi).
// Round-7 post-mortem: the 30720-tiny-block version cost ~50 us (dispatch-
// bound, 16x redundant input loads, cross-XCD writes). This version: 512
// blocks — SAME grid shape as lstm_fused, so block j writes r1blk(j) on the
// XCD that will re-read it (identical round-robin dispatch). Per iter t:
// thread (row=tid>>4, q=tid&15) computes 4 ch; wave stores 512B contiguous.
// Wi/bi hoisted to registers; no integer division anywhere. t ascending so
// t=59 (read first by LSTM1) is most L2-recent. x lives in r1buf slots that
// LSTM1 vacates t-descending (read-before-write per slot). ----
__global__ __launch_bounds__(TPB, 4)
void xgen(const float* __restrict__ inputs_main, const float* __restrict__ Wi,
          const float* __restrict__ bi, ushort_t* __restrict__ r1buf) {
  const int tid = threadIdx.x;
  const int row = tid >> 4, q = tid & 15;
  const int ch0 = q * 4;
  f4v wv0 = *(const f4v*)(Wi + (ch0 + 0) * 4) * T2L;
  f4v wv1 = *(const f4v*)(Wi + (ch0 + 1) * 4) * T2L;
  f4v wv2 = *(const f4v*)(Wi + (ch0 + 2) * 4) * T2L;
  f4v wv3 = *(const f4v*)(Wi + (ch0 + 3) * 4) * T2L;
  f4v bv  = *(const f4v*)(bi + ch0) * T2L;
  const float* src = inputs_main + ((size_t)blockIdx.x * ROWS + row) * 240;
  ushort_t* dst = r1buf + (size_t)blockIdx.x * 61440 + row * 64 + ch0 * 1;  // ushorts
#pragma unroll 4
  for (int t = 0; t < 60; ++t) {
    f4v xin = *(const f4v*)(src + t * 4);
    float a0 = fmaf(wv0[3], xin[3], fmaf(wv0[2], xin[2],
               fmaf(wv0[1], xin[1], fmaf(wv0[0], xin[0], bv[0]))));
    float a1 = fmaf(wv1[3], xin[3], fmaf(wv1[2], xin[2],
               fmaf(wv1[1], xin[1], fmaf(wv1[0], xin[0], bv[1]))));
    float a2 = fmaf(wv2[3], xin[3], fmaf(wv2[2], xin[2],
               fmaf(wv2[1], xin[1], fmaf(wv2[0], xin[0], bv[2]))));
    float a3 = fmaf(wv3[3], xin[3], fmaf(wv3[2], xin[2],
               fmaf(wv3[1], xin[1], fmaf(wv3[0], xin[0], bv[3]))));
    float x0 = fmaf(rcp_(1.0f + ex2_(a0)), -2.0f, 1.0f);
    float x1 = fmaf(rcp_(1.0f + ex2_(a1)), -2.0f, 1.0f);
    float x2 = fmaf(rcp_(1.0f + ex2_(a2)), -2.0f, 1.0f);
    float x3 = fmaf(rcp_(1.0f + ex2_(a3)), -2.0f, 1.0f);
    *(uint2*)(dst + t * 1024) = make_uint2(pkbf(x0, x1), pkbf(x2, x3));
  }
}

// ---- Fused LSTM: 512 blocks x 256 thr, 16 rows/block, 2 blocks/CU.
// x-generator hoisted to xgen pre-pass (round 7: lstm_fused 151.6->136.7 us,
// matched prediction). Unchanged this round. ----
__global__ __launch_bounds__(TPB, 2)
void lstm_fused(const float* __restrict__ inputs_aux,
                const float* __restrict__ rnn1_mem,
                const float* __restrict__ Ws1, const float* __restrict__ bs1,
                const float* __restrict__ Ws2, const float* __restrict__ bs2,
                const float* __restrict__ Wt1, const float* __restrict__ bt1,
                const float* __restrict__ Wt2, const float* __restrict__ bt2,
                const float* __restrict__ bih1, const float* __restrict__ bhh1,
                const float* __restrict__ bih2, const float* __restrict__ bhh2,
                const float* __restrict__ bl,  const float* __restrict__ Wo,
                const float* __restrict__ bo,  const float* __restrict__ bso,
                const ushort_t* __restrict__ frag,
                ushort_t* __restrict__ r1buf,
                float* __restrict__ out, float* __restrict__ out_sfc,
                float* __restrict__ new_mem) {
  const ushort_t* W1f = frag;
  const ushort_t* W2f = frag + 40960;
  const ushort_t* WlF = frag + 73728;
  const ushort_t* WcF = frag + 74752;
  const ushort_t* WsF = frag + 75776;

  __shared__ __align__(16) ushort_t xh[2][16 * SX];   // LSTM1: x|h1 ; LSTM2: r1|h2
  __shared__ __align__(16) ushort_t memAll[16 * SM];  // [row][t*16+m] bf16

  const int tid = threadIdx.x;
  const int lane = tid & 63, w = tid >> 6;
  const int ln = lane & 15, lq = lane >> 4;
  const int u = w * 16 + ln;
  const int rowbase = lq * 4;
  const int b0 = blockIdx.x * ROWS;
  const int rr8 = tid >> 3, ch8 = tid & 7;   // x prefetch (tid<128) / r1 stage

  ushort_t* r1blk = r1buf + (size_t)blockIdx.x * (60 * 16 * 64);

  // B1 fragments (prescaled weights)
  short8 B1f[4][5];
#pragma unroll
  for (int g = 0; g < 4; ++g)
#pragma unroll
    for (int ks = 0; ks < 5; ++ks)
      B1f[g][ks] = *(const short8*)(W1f + (((w * 4 + g) * 5 + ks) << 9) + (lane << 3));
  float bg1[4];
#pragma unroll
  for (int g = 0; g < 4; ++g)
    bg1[g] = (bih1[g * 64 + u] + bhh1[g * 64 + u]) * ((g == 2) ? T2L : LOG2E);

  // ---- stage static inputs; x(59) tile comes from xgen's output ----
  for (int e = tid; e < 16 * 240; e += TPB) {
    int r = e / 240, c = e - r * 240;
    f4v mv = *(const f4v*)(rnn1_mem + (size_t)(b0 + r) * 960 + c * 4);
    *(uint2*)&memAll[r * SM + c * 4] = make_uint2(pkbf(mv[0], mv[1]), pkbf(mv[2], mv[3]));
  }
  if (tid < 128) {   // x(59) -> xh[0] x-region (16 rows x 64 ch bf16)
    short8 xv = *(const short8*)(r1blk + 59 * 1024 + rr8 * 64 + ch8 * 8);
    *(short8*)&xh[0][rr8 * SX + ch8 * 8] = xv;
  }

  // ---- prologue: h1/c1 init into buffer 0 ----
  float ct1[4];   // cell state in 2*log2e-scaled domain
  {
    float w10 = Ws1[u * 3 + 0] * T2L, w11 = Ws1[u * 3 + 1] * T2L, w12 = Ws1[u * 3 + 2] * T2L;
    float bb1 = bs1[u] * T2L;
    float w20 = Ws2[u * 3 + 0] * T2L, w21 = Ws2[u * 3 + 1] * T2L, w22 = Ws2[u * 3 + 2] * T2L;
    float bb2 = bs2[u] * T2L;
#pragma unroll
    for (int reg = 0; reg < 4; ++reg) {
      int row = rowbase + reg;
      const float* ax = inputs_aux + (size_t)(b0 + row) * 3;
      float a0 = ax[0], a1 = ax[1], a2 = ax[2];
      float ha = w10 * a0 + w11 * a1 + w12 * a2 + bb1;
      xh[0][row * SX + 64 + u] = f2bu(fmaf(rcp_(1.0f + ex2_(ha)), -2.0f, 1.0f));
      float ca = w20 * a0 + w21 * a1 + w22 * a2 + bb2;
      ct1[reg] = fmaf(rcp_(1.0f + ex2_(ca)), -2.0f * T2L, T2L);
    }
  }
  __syncthreads();

  ushort_t* r1t = r1blk + rowbase * 64 + u;
  unsigned sxv[4], syv[4];
  int pb = 0;

  // ---- LSTM1: t = 59..0 in groups of 4; r1 flushed once per group ----
  for (int tg = 14; tg >= 0; --tg) {
#pragma unroll
    for (int s = 3; s >= 0; --s) {
      const int t = tg * 4 + s;
      const int nb = pb ^ 1;
      // prefetch x(t-1) from xgen output (slot not yet overwritten by r1)
      short8 xv;
      const bool lx = (t > 0) && (tid < 128);
      if (lx) xv = *(const short8*)(r1blk + (size_t)(t - 1) * 1024 + rr8 * 64 + ch8 * 8);

      const ushort_t* xrow = &xh[pb][ln * SX];
      short8 af0 = *(const short8*)(xrow + lq * 8);
      short8 af1 = *(const short8*)(xrow + 32 + lq * 8);
      short8 af2 = *(const short8*)(xrow + 64 + lq * 8);
      short8 af3 = *(const short8*)(xrow + 96 + lq * 8);
      short8 af4 = {};
      if (lq < 2) af4 = *(const short8*)(memAll + ln * SM + t * 16 + lq * 8);

      f32x4 acc[4];
#pragma unroll
      for (int g = 0; g < 4; ++g) acc[g] = (f32x4){bg1[g], bg1[g], bg1[g], bg1[g]};
      __builtin_amdgcn_s_setprio(1);
#pragma unroll
      for (int g = 0; g < 4; ++g) {
        acc[g] = mfma16(af0, B1f[g][0], acc[g]);
        acc[g] = mfma16(af1, B1f[g][1], acc[g]);
        acc[g] = mfma16(af2, B1f[g][2], acc[g]);
        acc[g] = mfma16(af3, B1f[g][3], acc[g]);
        acc[g] = mfma16(af4, B1f[g][4], acc[g]);
      }
      __builtin_amdgcn_s_setprio(0);

      float h[4];
#pragma unroll
      for (int reg = 0; reg < 4; ++reg) {
        float si = rcp_(1.0f + ex2_(-acc[0][reg]));
        float sf = rcp_(1.0f + ex2_(-acc[1][reg]));
        float so = rcp_(1.0f + ex2_(-acc[3][reg]));
        float gt = fmaf(rcp_(1.0f + ex2_(acc[2][reg])), -2.0f * T2L, T2L);
        ct1[reg] = fmaf(sf, ct1[reg], si * gt);
        float tc = fmaf(rcp_(1.0f + ex2_(ct1[reg])), -2.0f, 1.0f);
        h[reg] = so * tc;
      }
      unsigned h01 = pkbf(h[0], h[1]), h23 = pkbf(h[2], h[3]);
      sxv[s] = h01; syv[s] = h23;              // stash; flush after the group
      if (t > 0) {
        xh[nb][(rowbase + 0) * SX + 64 + u] = (ushort_t)h01;
        xh[nb][(rowbase + 1) * SX + 64 + u] = (ushort_t)(h01 >> 16);
        xh[nb][(rowbase + 2) * SX + 64 + u] = (ushort_t)h23;
        xh[nb][(rowbase + 3) * SX + 64 + u] = (ushort_t)(h23 >> 16);
      } else {                                  // r1(0) seeds LSTM2 input region
        xh[nb][(rowbase + 0) * SX + u] = (ushort_t)h01;
        xh[nb][(rowbase + 1) * SX + u] = (ushort_t)(h01 >> 16);
        xh[nb][(rowbase + 2) * SX + u] = (ushort_t)h23;
        xh[nb][(rowbase + 3) * SX + u] = (ushort_t)(h23 >> 16);
      }
      if (lx) *(short8*)&xh[nb][rr8 * SX + ch8 * 8] = xv;   // x(t-1) into next buf
      BAR();
      pb = nb;
    }
    // flush r1 for tt = tg*4 .. tg*4+3 (retires in background; no barrier drain)
    ushort_t* rp = r1t + (tg << 12);
#pragma unroll
    for (int s = 0; s < 4; ++s) {
      unsigned a = sxv[s], b = syv[s];
      rp[s * 1024 + 0 * 64] = (ushort_t)a;
      rp[s * 1024 + 1 * 64] = (ushort_t)(a >> 16);
      rp[s * 1024 + 2 * 64] = (ushort_t)b;
      rp[s * 1024 + 3 * 64] = (ushort_t)(b >> 16);
    }
  }

  // ---- LSTM2 setup ----
  short8 B2f[4][4];
#pragma unroll
  for (int g = 0; g < 4; ++g)
#pragma unroll
    for (int ks = 0; ks < 4; ++ks)
      B2f[g][ks] = *(const short8*)(W2f + (((w * 4 + g) * 4 + ks) << 9) + (lane << 3));
  float bg2[4];
#pragma unroll
  for (int g = 0; g < 4; ++g)
    bg2[g] = (bih2[g * 64 + u] + bhh2[g * 64 + u]) * ((g == 2) ? T2L : LOG2E);

  float ct2[4];
  {
    float wt1u = Wt1[u], wt2u = Wt2[u], bt1u = bt1[u], bt2u = bt2[u];
#pragma unroll
    for (int reg = 0; reg < 4; ++reg) {
      int row = rowbase + reg;
      float toa = inputs_aux[(size_t)(b0 + row) * 3 + 1];
      xh[pb][row * SX + 64 + u] = f2bu(toa * wt1u + bt1u);   // no tanh (ref)
      ct2[reg] = (toa * wt2u + bt2u) * T2L;
    }
  }
  short8 PW0 = {}, PW1 = {};
  float pbias = 0.0f;
  if (w == 0) {
    PW0 = *(const short8*)(WlF + (lane << 3));
    PW1 = *(const short8*)(WlF + 512 + (lane << 3));
    pbias = bl[ln];
  } else if (w == 1) {
    PW0 = *(const short8*)(WcF + (lane << 3));
    PW1 = *(const short8*)(WcF + 512 + (lane << 3));
    if (ln < 4) {
      float a = bo[ln];
#pragma unroll
      for (int m = 0; m < 16; ++m) a += Wo[ln * 16 + m] * bl[m];
      pbias = a;
    }
  } else if (w == 2) {
    PW0 = *(const short8*)(WsF + (lane << 3));
    PW1 = *(const short8*)(WsF + 512 + (lane << 3));
    pbias = (ln < 3) ? bso[ln] : 0.0f;
  }
  const ushort_t* r1rp = r1blk + 1024 + rr8 * 64 + ch8 * 8;
  float* nmb = new_mem + (size_t)(b0 + rowbase) * 960 + ln;
  float* outb = out + (size_t)(b0 + rowbase) * 240 + ln;
  f32x4 pst[4];
  __syncthreads();   // FULL barrier: drains r1 global writes before re-reads

  // ---- LSTM2: t = 0..59 in groups of 4; proj stores flushed per group ----
  for (int tg = 0; tg < 15; ++tg) {
#pragma unroll
    for (int s = 0; s < 4; ++s) {
      const int t = tg * 4 + s;
      const int nb = pb ^ 1;
      short8 r1v = {};
      if (t < 59 && tid < 128) r1v = *(const short8*)(r1rp + t * 1024);

      const ushort_t* xrow = &xh[pb][ln * SX];
      short8 af0 = *(const short8*)(xrow + lq * 8);
      short8 af1 = *(const short8*)(xrow + 32 + lq * 8);
      short8 af2 = *(const short8*)(xrow + 64 + lq * 8);
      short8 af3 = *(const short8*)(xrow + 96 + lq * 8);

      f32x4 acc[4];
#pragma unroll
      for (int g = 0; g < 4; ++g) acc[g] = (f32x4){bg2[g], bg2[g], bg2[g], bg2[g]};
      __builtin_amdgcn_s_setprio(1);
#pragma unroll
      for (int g = 0; g < 4; ++g) {
        acc[g] = mfma16(af0, B2f[g][0], acc[g]);
        acc[g] = mfma16(af1, B2f[g][1], acc[g]);
        acc[g] = mfma16(af2, B2f[g][2], acc[g]);
        acc[g] = mfma16(af3, B2f[g][3], acc[g]);
      }

      if (t > 0 && w < 2) {  // projection of h2(t-1) — reuses af2/af3
        f32x4 ap = (f32x4){pbias, pbias, pbias, pbias};
        ap = mfma16(af2, PW0, ap);
        ap = mfma16(af3, PW1, ap);
        pst[(t - 1) & 3] = ap;
      }
      __builtin_amdgcn_s_setprio(0);

      float h[4];
#pragma unroll
      for (int reg = 0; reg < 4; ++reg) {
        float si = rcp_(1.0f + ex2_(-acc[0][reg]));
        float sf = rcp_(1.0f + ex2_(-acc[1][reg]));
        float so = rcp_(1.0f + ex2_(-acc[3][reg]));
        float gt = fmaf(rcp_(1.0f + ex2_(acc[2][reg])), -2.0f * T2L, T2L);
        ct2[reg] = fmaf(sf, ct2[reg], si * gt);
        float tc = fmaf(rcp_(1.0f + ex2_(ct2[reg])), -2.0f, 1.0f);
        h[reg] = so * tc;
      }
      unsigned h01 = pkbf(h[0], h[1]), h23 = pkbf(h[2], h[3]);
      xh[nb][(rowbase + 0) * SX + 64 + u] = (ushort_t)h01;
      xh[nb][(rowbase + 1) * SX + 64 + u] = (ushort_t)(h01 >> 16);
      xh[nb][(rowbase + 2) * SX + 64 + u] = (ushort_t)h23;
      xh[nb][(rowbase + 3) * SX + 64 + u] = (ushort_t)(h23 >> 16);
      if (t < 59 && tid < 128)
        *(short8*)&xh[nb][rr8 * SX + ch8 * 8] = r1v;
      BAR();
      pb = nb;
    }
    // flush projections: slots 0,1,2 -> pt = tg*4+{0,1,2}; slot 3 -> pt = tg*4-1
    if (w < 2) {
      const int base = tg * 4;
#pragma unroll
      for (int k = 0; k < 4; ++k) {
        const int pt = (k == 3) ? base - 1 : base + k;
        if (pt < 0) continue;
        f32x4 ap = pst[k];
        if (w == 0) {
#pragma unroll
          for (int reg = 0; reg < 4; ++reg) nmb[reg * 960 + pt * 16] = ap[reg];
        } else if (ln < 4) {
#pragma unroll
          for (int reg = 0; reg < 4; ++reg) outb[reg * 240 + pt * 4] = ap[reg];
        }
      }
    }
  }

  // ---- tail: pt = 59 projections + out_sfc from final h2 (xh[pb]) ----
  if (w < 3) {
    const ushort_t* xrow = &xh[pb][ln * SX];
    short8 aL0 = *(const short8*)(xrow + 64 + lq * 8);
    short8 aL1 = *(const short8*)(xrow + 96 + lq * 8);
    f32x4 ap = (f32x4){pbias, pbias, pbias, pbias};
    ap = mfma16(aL0, PW0, ap);
    ap = mfma16(aL1, PW1, ap);
    if (w == 0) {
#pragma unroll
      for (int reg = 0; reg < 4; ++reg) nmb[reg * 960 + 59 * 16] = ap[reg];
    } else if (w == 1) {
      if (ln < 4) {
#pragma unroll
        for (int reg = 0; reg < 4; ++reg) outb[reg * 240 + 59 * 4] = ap[reg];
      }
    } else {
      if (ln < 3) {
#pragma unroll
        for (int reg = 0; reg < 4; ++reg)
          out_sfc[(size_t)(b0 + rowbase + reg) * 3 + ln] = ap[reg];
      }
    }
  }
}

extern "C" void kernel_launch(void* const* d_in, const int* in_sizes, int n_in,
                              void* d_out, int out_size, void* d_ws, size_t ws_size,
                              hipStream_t stream) {
  (void)in_sizes; (void)n_in; (void)out_size; (void)ws_size;
  const float* inputs_main = (const float*)d_in[0];
  const float* inputs_aux  = (const float*)d_in[1];
  const float* rnn1_mem    = (const float*)d_in[2];
  const float* Wi   = (const float*)d_in[3];
  const float* bi   = (const float*)d_in[4];
  const float* Ws1  = (const float*)d_in[5];
  const float* bs1  = (const float*)d_in[6];
  const float* Ws2  = (const float*)d_in[7];
  const float* bs2  = (const float*)d_in[8];
  const float* Wt1  = (const float*)d_in[9];
  const float* bt1  = (const float*)d_in[10];
  const float* Wt2  = (const float*)d_in[11];
  const float* bt2  = (const float*)d_in[12];
  const float* Wih1 = (const float*)d_in[13];
  const float* Whh1 = (const float*)d_in[14];
  const float* bih1 = (const float*)d_in[15];
  const float* bhh1 = (const float*)d_in[16];
  const float* Wih2 = (const float*)d_in[17];
  const float* Whh2 = (const float*)d_in[18];
  const float* bih2 = (const float*)d_in[19];
  const float* bhh2 = (const float*)d_in[20];
  const float* Wl   = (const float*)d_in[21];
  const float* bl   = (const float*)d_in[22];
  const float* Wo   = (const float*)d_in[23];
  const float* bo   = (const float*)d_in[24];
  const float* Wso  = (const float*)d_in[25];
  const float* bso  = (const float*)d_in[26];

  float* out     = (float*)d_out;
  float* out_sfc = out + (size_t)BATCH * NLAY * 4;
  float* new_mem = out_sfc + (size_t)BATCH * 3;

  ushort_t* frag  = (ushort_t*)d_ws;                          // 76800 ushorts
  ushort_t* r1buf = (ushort_t*)((char*)d_ws + 153600);        // [block][60][16][64] bf16
                                                              // (x prestage, then r1)

  wtranspose<<<300, 256, 0, stream>>>(Wih1, Whh1, Wih2, Whh2, Wl, Wo, Wso, frag);
  xgen<<<BATCH / ROWS, TPB, 0, stream>>>(inputs_main, Wi, bi, r1buf);
  lstm_fused<<<BATCH / ROWS, TPB, 0, stream>>>(
      inputs_aux, rnn1_mem, Ws1, bs1, Ws2, bs2,
      Wt1, bt1, Wt2, bt2, bih1, bhh1, bih2, bhh2, bl, Wo, bo, bso,
      frag, r1buf, out, out_sfc, new_mem);
}

// Round 9
// 266.516 us; speedup vs baseline: 1.1009x; 1.0165x over previous
//
#include <hip/hip_runtime.h>
#include <hip/hip_bf16.h>

#define BATCH 8192
#define NLAY  60
#define ROWS  16
#define TPB   256
#define SX    136     // xh row stride (ushort)
#define SM    968     // memAll row stride (ushort)
#define LOG2E 1.44269504089f
#define T2L   2.88539008178f

typedef unsigned short ushort_t;
typedef __attribute__((ext_vector_type(8))) short short8;
typedef __attribute__((ext_vector_type(4))) float f32x4;
typedef __attribute__((ext_vector_type(4))) float f4v;

__device__ __forceinline__ float rcp_(float x) { return __builtin_amdgcn_rcpf(x); }
__device__ __forceinline__ float ex2_(float x) { return __builtin_amdgcn_exp2f(x); }
__device__ __forceinline__ ushort_t f2bu(float f) {
  unsigned u = __float_as_uint(f);
  return (ushort_t)((u + 0x7FFFu + ((u >> 16) & 1u)) >> 16);
}
__device__ __forceinline__ unsigned pkbf(float a, float b) {
  union { __hip_bfloat162 h; unsigned u; } c;
  c.h = __float22bfloat162_rn(make_float2(a, b));
  return c.u;
}
__device__ __forceinline__ f32x4 mfma16(short8 a, short8 b, f32x4 c) {
  return __builtin_amdgcn_mfma_f32_16x16x32_bf16(a, b, c, 0, 0, 0);
}
// LDS-only barrier (global stores stay in flight; full __syncthreads only at
// the LSTM1->LSTM2 transition where the block re-reads its own r1 stores).
#define BAR() asm volatile("s_waitcnt lgkmcnt(0)\n\ts_barrier" ::: "memory")

// ---- Pre-pass: pack weights into MFMA B-fragment order (bf16 bits) ----
// LSTM1 K-order: [x 0..63 | h 64..127 | mem 128..143 | pad 144..159]
// Gate weights PRE-SCALED: i,f,o by log2e ; g by 2*log2e (exp2-domain epilogue).
// W1f [w][g][ks5][512] @0 ; W2f [w][g][ks4][512] @40960 ; WlF @73728 ;
// WcF (Wo@Wl) @74752 ; WsF (Wso) @75776. Total 76800 ushorts.
__global__ void wtranspose(const float* __restrict__ Wih1, const float* __restrict__ Whh1,
                           const float* __restrict__ Wih2, const float* __restrict__ Whh2,
                           const float* __restrict__ Wl,   const float* __restrict__ Wo,
                           const float* __restrict__ Wso,  ushort_t* __restrict__ frag) {
  int e = blockIdx.x * 256 + threadIdx.x;
  float v;
  if (e < 40960) {
    int j = e & 7, lx = (e >> 3) & 63, rest = e >> 9;
    int ks = rest % 5, gw = rest / 5;
    int g = gw & 3, wv = gw >> 2;
    int row = g * 64 + wv * 16 + (lx & 15);
    int k = ks * 32 + (lx >> 4) * 8 + j;
    v = (k < 64)  ? Wih1[row * 80 + k]
      : (k < 128) ? Whh1[row * 64 + (k - 64)]
      : (k < 144) ? Wih1[row * 80 + 64 + (k - 128)]
      : 0.0f;
    v *= (g == 2) ? T2L : LOG2E;
  } else if (e < 73728) {
    int e2 = e - 40960;
    int j = e2 & 7, lx = (e2 >> 3) & 63, rest = e2 >> 9;
    int ks = rest & 3, g = (rest >> 2) & 3, wv = rest >> 4;
    int row = g * 64 + wv * 16 + (lx & 15);
    int k = ks * 32 + (lx >> 4) * 8 + j;
    v = (k < 64) ? Wih2[row * 64 + k] : Whh2[row * 64 + (k - 64)];
    v *= (g == 2) ? T2L : LOG2E;
  } else if (e < 74752) {
    int e3 = e - 73728;
    int j = e3 & 7, lx = (e3 >> 3) & 63, ks = e3 >> 9;
    int n = lx & 15, k = ks * 32 + (lx >> 4) * 8 + j;
    v = Wl[n * 64 + k];
  } else if (e < 75776) {
    int e4 = e - 74752;
    int j = e4 & 7, lx = (e4 >> 3) & 63, ks = e4 >> 9;
    int n = lx & 15, k = ks * 32 + (lx >> 4) * 8 + j;
    v = 0.0f;
    if (n < 4) {
#pragma unroll
      for (int m = 0; m < 16; ++m) v += Wo[n * 16 + m] * Wl[m * 64 + k];
    }
  } else {
    int e5 = e - 75776;
    int j = e5 & 7, lx = (e5 >> 3) & 63, ks = e5 >> 9;
    int n = lx & 15, k = ks * 32 + (lx >> 4) * 8 + j;
    v = (n < 3) ? Wso[n * 64 + k] : 0.0f;
  }
  frag[e] = f2bu(v);
}

// ---- Fused LSTM: 512 blocks x 256 thr, 16 rows/block, 2 blocks/CU.
// Round-8 accounting: separate xgen kernel cost ~31 us (launch + full
// serialization before lstm could start) while lstm already paid the x
// read-back. This round: x-generation fused into the PROLOGUE — each block
// generates x for its own 16 rows (thread (row=tid>>4, q=tid&15), 60 iters),
// writes t=0..58 into its own r1blk x-slots (123 KB, overlaps memAll
// staging), t=59 straight to LDS. Prologue __syncthreads (full vmcnt drain)
// orders writes before first read-back; slot time-share (x read-before-r1-
// write per slot, t descending) unchanged from round 8. ----
__global__ __launch_bounds__(TPB, 2)
void lstm_fused(const float* __restrict__ inputs_main,
                const float* __restrict__ inputs_aux,
                const float* __restrict__ rnn1_mem,
                const float* __restrict__ Wi,  const float* __restrict__ bi,
                const float* __restrict__ Ws1, const float* __restrict__ bs1,
                const float* __restrict__ Ws2, const float* __restrict__ bs2,
                const float* __restrict__ Wt1, const float* __restrict__ bt1,
                const float* __restrict__ Wt2, const float* __restrict__ bt2,
                const float* __restrict__ bih1, const float* __restrict__ bhh1,
                const float* __restrict__ bih2, const float* __restrict__ bhh2,
                const float* __restrict__ bl,  const float* __restrict__ Wo,
                const float* __restrict__ bo,  const float* __restrict__ bso,
                const ushort_t* __restrict__ frag,
                ushort_t* __restrict__ r1buf,
                float* __restrict__ out, float* __restrict__ out_sfc,
                float* __restrict__ new_mem) {
  const ushort_t* W1f = frag;
  const ushort_t* W2f = frag + 40960;
  const ushort_t* WlF = frag + 73728;
  const ushort_t* WcF = frag + 74752;
  const ushort_t* WsF = frag + 75776;

  __shared__ __align__(16) ushort_t xh[2][16 * SX];   // LSTM1: x|h1 ; LSTM2: r1|h2
  __shared__ __align__(16) ushort_t memAll[16 * SM];  // [row][t*16+m] bf16

  const int tid = threadIdx.x;
  const int lane = tid & 63, w = tid >> 6;
  const int ln = lane & 15, lq = lane >> 4;
  const int u = w * 16 + ln;
  const int rowbase = lq * 4;
  const int b0 = blockIdx.x * ROWS;
  const int rr8 = tid >> 3, ch8 = tid & 7;   // x prefetch (tid<128) / r1 stage

  ushort_t* r1blk = r1buf + (size_t)blockIdx.x * (60 * 16 * 64);

  // B1 fragments (prescaled weights)
  short8 B1f[4][5];
#pragma unroll
  for (int g = 0; g < 4; ++g)
#pragma unroll
    for (int ks = 0; ks < 5; ++ks)
      B1f[g][ks] = *(const short8*)(W1f + (((w * 4 + g) * 5 + ks) << 9) + (lane << 3));
  float bg1[4];
#pragma unroll
  for (int g = 0; g < 4; ++g)
    bg1[g] = (bih1[g * 64 + u] + bhh1[g * 64 + u]) * ((g == 2) ? T2L : LOG2E);

  // ---- stage static inputs ----
  for (int e = tid; e < 16 * 240; e += TPB) {
    int r = e / 240, c = e - r * 240;
    f4v mv = *(const f4v*)(rnn1_mem + (size_t)(b0 + r) * 960 + c * 4);
    *(uint2*)&memAll[r * SM + c * 4] = make_uint2(pkbf(mv[0], mv[1]), pkbf(mv[2], mv[3]));
  }

  // ---- x-gen prologue: x(b,t,c) = tanh(Wi@inputs_main + bi) for this
  // block's 16 rows; t=0..58 -> r1blk x-slots (global), t=59 -> LDS. ----
  {
    const int xr = tid >> 4, xq = tid & 15, ch0 = xq * 4;
    f4v wv0 = *(const f4v*)(Wi + (ch0 + 0) * 4) * T2L;
    f4v wv1 = *(const f4v*)(Wi + (ch0 + 1) * 4) * T2L;
    f4v wv2 = *(const f4v*)(Wi + (ch0 + 2) * 4) * T2L;
    f4v wv3 = *(const f4v*)(Wi + (ch0 + 3) * 4) * T2L;
    f4v bv  = *(const f4v*)(bi + ch0) * T2L;
    const float* src = inputs_main + (size_t)(b0 + xr) * 240;
    ushort_t* dst = r1blk + xr * 64 + ch0;
#pragma unroll 4
    for (int t = 0; t < 60; ++t) {
      f4v xin = *(const f4v*)(src + t * 4);
      float a0 = fmaf(wv0[3], xin[3], fmaf(wv0[2], xin[2],
                 fmaf(wv0[1], xin[1], fmaf(wv0[0], xin[0], bv[0]))));
      float a1 = fmaf(wv1[3], xin[3], fmaf(wv1[2], xin[2],
                 fmaf(wv1[1], xin[1], fmaf(wv1[0], xin[0], bv[1]))));
      float a2 = fmaf(wv2[3], xin[3], fmaf(wv2[2], xin[2],
                 fmaf(wv2[1], xin[1], fmaf(wv2[0], xin[0], bv[2]))));
      float a3 = fmaf(wv3[3], xin[3], fmaf(wv3[2], xin[2],
                 fmaf(wv3[1], xin[1], fmaf(wv3[0], xin[0], bv[3]))));
      float x0 = fmaf(rcp_(1.0f + ex2_(a0)), -2.0f, 1.0f);
      float x1 = fmaf(rcp_(1.0f + ex2_(a1)), -2.0f, 1.0f);
      float x2 = fmaf(rcp_(1.0f + ex2_(a2)), -2.0f, 1.0f);
      float x3 = fmaf(rcp_(1.0f + ex2_(a3)), -2.0f, 1.0f);
      uint2 pk = make_uint2(pkbf(x0, x1), pkbf(x2, x3));
      if (t < 59) *(uint2*)(dst + t * 1024) = pk;
      else        *(uint2*)&xh[0][xr * SX + ch0] = pk;   // x(59) straight to LDS
    }
  }

  // ---- prologue: h1/c1 init into buffer 0 ----
  float ct1[4];   // cell state in 2*log2e-scaled domain
  {
    float w10 = Ws1[u * 3 + 0] * T2L, w11 = Ws1[u * 3 + 1] * T2L, w12 = Ws1[u * 3 + 2] * T2L;
    float bb1 = bs1[u] * T2L;
    float w20 = Ws2[u * 3 + 0] * T2L, w21 = Ws2[u * 3 + 1] * T2L, w22 = Ws2[u * 3 + 2] * T2L;
    float bb2 = bs2[u] * T2L;
#pragma unroll
    for (int reg = 0; reg < 4; ++reg) {
      int row = rowbase + reg;
      const float* ax = inputs_aux + (size_t)(b0 + row) * 3;
      float a0 = ax[0], a1 = ax[1], a2 = ax[2];
      float ha = w10 * a0 + w11 * a1 + w12 * a2 + bb1;
      xh[0][row * SX + 64 + u] = f2bu(fmaf(rcp_(1.0f + ex2_(ha)), -2.0f, 1.0f));
      float ca = w20 * a0 + w21 * a1 + w22 * a2 + bb2;
      ct1[reg] = fmaf(rcp_(1.0f + ex2_(ca)), -2.0f * T2L, T2L);
    }
  }
  __syncthreads();   // full drain: x writes visible before read-back

  ushort_t* r1t = r1blk + rowbase * 64 + u;
  unsigned sxv[4], syv[4];
  int pb = 0;

  // ---- LSTM1: t = 59..0 in groups of 4; r1 flushed once per group ----
  for (int tg = 14; tg >= 0; --tg) {
#pragma unroll
    for (int s = 3; s >= 0; --s) {
      const int t = tg * 4 + s;
      const int nb = pb ^ 1;
      // prefetch x(t-1) from prologue output (slot not yet overwritten by r1)
      short8 xv;
      const bool lx = (t > 0) && (tid < 128);
      if (lx) xv = *(const short8*)(r1blk + (size_t)(t - 1) * 1024 + rr8 * 64 + ch8 * 8);

      const ushort_t* xrow = &xh[pb][ln * SX];
      short8 af0 = *(const short8*)(xrow + lq * 8);
      short8 af1 = *(const short8*)(xrow + 32 + lq * 8);
      short8 af2 = *(const short8*)(xrow + 64 + lq * 8);
      short8 af3 = *(const short8*)(xrow + 96 + lq * 8);
      short8 af4 = {};
      if (lq < 2) af4 = *(const short8*)(memAll + ln * SM + t * 16 + lq * 8);

      f32x4 acc[4];
#pragma unroll
      for (int g = 0; g < 4; ++g) acc[g] = (f32x4){bg1[g], bg1[g], bg1[g], bg1[g]};
      __builtin_amdgcn_s_setprio(1);
#pragma unroll
      for (int g = 0; g < 4; ++g) {
        acc[g] = mfma16(af0, B1f[g][0], acc[g]);
        acc[g] = mfma16(af1, B1f[g][1], acc[g]);
        acc[g] = mfma16(af2, B1f[g][2], acc[g]);
        acc[g] = mfma16(af3, B1f[g][3], acc[g]);
        acc[g] = mfma16(af4, B1f[g][4], acc[g]);
      }
      __builtin_amdgcn_s_setprio(0);

      float h[4];
#pragma unroll
      for (int reg = 0; reg < 4; ++reg) {
        float si = rcp_(1.0f + ex2_(-acc[0][reg]));
        float sf = rcp_(1.0f + ex2_(-acc[1][reg]));
        float so = rcp_(1.0f + ex2_(-acc[3][reg]));
        float gt = fmaf(rcp_(1.0f + ex2_(acc[2][reg])), -2.0f * T2L, T2L);
        ct1[reg] = fmaf(sf, ct1[reg], si * gt);
        float tc = fmaf(rcp_(1.0f + ex2_(ct1[reg])), -2.0f, 1.0f);
        h[reg] = so * tc;
      }
      unsigned h01 = pkbf(h[0], h[1]), h23 = pkbf(h[2], h[3]);
      sxv[s] = h01; syv[s] = h23;              // stash; flush after the group
      if (t > 0) {
        xh[nb][(rowbase + 0) * SX + 64 + u] = (ushort_t)h01;
        xh[nb][(rowbase + 1) * SX + 64 + u] = (ushort_t)(h01 >> 16);
        xh[nb][(rowbase + 2) * SX + 64 + u] = (ushort_t)h23;
        xh[nb][(rowbase + 3) * SX + 64 + u] = (ushort_t)(h23 >> 16);
      } else {                                  // r1(0) seeds LSTM2 input region
        xh[nb][(rowbase + 0) * SX + u] = (ushort_t)h01;
        xh[nb][(rowbase + 1) * SX + u] = (ushort_t)(h01 >> 16);
        xh[nb][(rowbase + 2) * SX + u] = (ushort_t)h23;
        xh[nb][(rowbase + 3) * SX + u] = (ushort_t)(h23 >> 16);
      }
      if (lx) *(short8*)&xh[nb][rr8 * SX + ch8 * 8] = xv;   // x(t-1) into next buf
      BAR();
      pb = nb;
    }
    // flush r1 for tt = tg*4 .. tg*4+3 (retires in background; no barrier drain)
    ushort_t* rp = r1t + (tg << 12);
#pragma unroll
    for (int s = 0; s < 4; ++s) {
      unsigned a = sxv[s], b = syv[s];
      rp[s * 1024 + 0 * 64] = (ushort_t)a;
      rp[s * 1024 + 1 * 64] = (ushort_t)(a >> 16);
      rp[s * 1024 + 2 * 64] = (ushort_t)b;
      rp[s * 1024 + 3 * 64] = (ushort_t)(b >> 16);
    }
  }

  // ---- LSTM2 setup ----
  short8 B2f[4][4];
#pragma unroll
  for (int g = 0; g < 4; ++g)
#pragma unroll
    for (int ks = 0; ks < 4; ++ks)
      B2f[g][ks] = *(const short8*)(W2f + (((w * 4 + g) * 4 + ks) << 9) + (lane << 3));
  float bg2[4];
#pragma unroll
  for (int g = 0; g < 4; ++g)
    bg2[g] = (bih2[g * 64 + u] + bhh2[g * 64 + u]) * ((g == 2) ? T2L : LOG2E);

  float ct2[4];
  {
    float wt1u = Wt1[u], wt2u = Wt2[u], bt1u = bt1[u], bt2u = bt2[u];
#pragma unroll
    for (int reg = 0; reg < 4; ++reg) {
      int row = rowbase + reg;
      float toa = inputs_aux[(size_t)(b0 + row) * 3 + 1];
      xh[pb][row * SX + 64 + u] = f2bu(toa * wt1u + bt1u);   // no tanh (ref)
      ct2[reg] = (toa * wt2u + bt2u) * T2L;
    }
  }
  short8 PW0 = {}, PW1 = {};
  float pbias = 0.0f;
  if (w == 0) {
    PW0 = *(const short8*)(WlF + (lane << 3));
    PW1 = *(const short8*)(WlF + 512 + (lane << 3));
    pbias = bl[ln];
  } else if (w == 1) {
    PW0 = *(const short8*)(WcF + (lane << 3));
    PW1 = *(const short8*)(WcF + 512 + (lane << 3));
    if (ln < 4) {
      float a = bo[ln];
#pragma unroll
      for (int m = 0; m < 16; ++m) a += Wo[ln * 16 + m] * bl[m];
      pbias = a;
    }
  } else if (w == 2) {
    PW0 = *(const short8*)(WsF + (lane << 3));
    PW1 = *(const short8*)(WsF + 512 + (lane << 3));
    pbias = (ln < 3) ? bso[ln] : 0.0f;
  }
  const ushort_t* r1rp = r1blk + 1024 + rr8 * 64 + ch8 * 8;
  float* nmb = new_mem + (size_t)(b0 + rowbase) * 960 + ln;
  float* outb = out + (size_t)(b0 + rowbase) * 240 + ln;
  f32x4 pst[4];
  __syncthreads();   // FULL barrier: drains r1 global writes before re-reads

  // ---- LSTM2: t = 0..59 in groups of 4; proj stores flushed per group ----
  for (int tg = 0; tg < 15; ++tg) {
#pragma unroll
    for (int s = 0; s < 4; ++s) {
      const int t = tg * 4 + s;
      const int nb = pb ^ 1;
      short8 r1v = {};
      if (t < 59 && tid < 128) r1v = *(const short8*)(r1rp + t * 1024);

      const ushort_t* xrow = &xh[pb][ln * SX];
      short8 af0 = *(const short8*)(xrow + lq * 8);
      short8 af1 = *(const short8*)(xrow + 32 + lq * 8);
      short8 af2 = *(const short8*)(xrow + 64 + lq * 8);
      short8 af3 = *(const short8*)(xrow + 96 + lq * 8);

      f32x4 acc[4];
#pragma unroll
      for (int g = 0; g < 4; ++g) acc[g] = (f32x4){bg2[g], bg2[g], bg2[g], bg2[g]};
      __builtin_amdgcn_s_setprio(1);
#pragma unroll
      for (int g = 0; g < 4; ++g) {
        acc[g] = mfma16(af0, B2f[g][0], acc[g]);
        acc[g] = mfma16(af1, B2f[g][1], acc[g]);
        acc[g] = mfma16(af2, B2f[g][2], acc[g]);
        acc[g] = mfma16(af3, B2f[g][3], acc[g]);
      }

      if (t > 0 && w < 2) {  // projection of h2(t-1) — reuses af2/af3
        f32x4 ap = (f32x4){pbias, pbias, pbias, pbias};
        ap = mfma16(af2, PW0, ap);
        ap = mfma16(af3, PW1, ap);
        pst[(t - 1) & 3] = ap;
      }
      __builtin_amdgcn_s_setprio(0);

      float h[4];
#pragma unroll
      for (int reg = 0; reg < 4; ++reg) {
        float si = rcp_(1.0f + ex2_(-acc[0][reg]));
        float sf = rcp_(1.0f + ex2_(-acc[1][reg]));
        float so = rcp_(1.0f + ex2_(-acc[3][reg]));
        float gt = fmaf(rcp_(1.0f + ex2_(acc[2][reg])), -2.0f * T2L, T2L);
        ct2[reg] = fmaf(sf, ct2[reg], si * gt);
        float tc = fmaf(rcp_(1.0f + ex2_(ct2[reg])), -2.0f, 1.0f);
        h[reg] = so * tc;
      }
      unsigned h01 = pkbf(h[0], h[1]), h23 = pkbf(h[2], h[3]);
      xh[nb][(rowbase + 0) * SX + 64 + u] = (ushort_t)h01;
      xh[nb][(rowbase + 1) * SX + 64 + u] = (ushort_t)(h01 >> 16);
      xh[nb][(rowbase + 2) * SX + 64 + u] = (ushort_t)h23;
      xh[nb][(rowbase + 3) * SX + 64 + u] = (ushort_t)(h23 >> 16);
      if (t < 59 && tid < 128)
        *(short8*)&xh[nb][rr8 * SX + ch8 * 8] = r1v;
      BAR();
      pb = nb;
    }
    // flush projections: slots 0,1,2 -> pt = tg*4+{0,1,2}; slot 3 -> pt = tg*4-1
    if (w < 2) {
      const int base = tg * 4;
#pragma unroll
      for (int k = 0; k < 4; ++k) {
        const int pt = (k == 3) ? base - 1 : base + k;
        if (pt < 0) continue;
        f32x4 ap = pst[k];
        if (w == 0) {
#pragma unroll
          for (int reg = 0; reg < 4; ++reg) nmb[reg * 960 + pt * 16] = ap[reg];
        } else if (ln < 4) {
#pragma unroll
          for (int reg = 0; reg < 4; ++reg) outb[reg * 240 + pt * 4] = ap[reg];
        }
      }
    }
  }

  // ---- tail: pt = 59 projections + out_sfc from final h2 (xh[pb]) ----
  if (w < 3) {
    const ushort_t* xrow = &xh[pb][ln * SX];
    short8 aL0 = *(const short8*)(xrow + 64 + lq * 8);
    short8 aL1 = *(const short8*)(xrow + 96 + lq * 8);
    f32x4 ap = (f32x4){pbias, pbias, pbias, pbias};
    ap = mfma16(aL0, PW0, ap);
    ap = mfma16(aL1, PW1, ap);
    if (w == 0) {
#pragma unroll
      for (int reg = 0; reg < 4; ++reg) nmb[reg * 960 + 59 * 16] = ap[reg];
    } else if (w == 1) {
      if (ln < 4) {
#pragma unroll
        for (int reg = 0; reg < 4; ++reg) outb[reg * 240 + 59 * 4] = ap[reg];
      }
    } else {
      if (ln < 3) {
#pragma unroll
        for (int reg = 0; reg < 4; ++reg)
          out_sfc[(size_t)(b0 + rowbase + reg) * 3 + ln] = ap[reg];
      }
    }
  }
}

extern "C" void kernel_launch(void* const* d_in, const int* in_sizes, int n_in,
                              void* d_out, int out_size, void* d_ws, size_t ws_size,
                              hipStream_t stream) {
  (void)in_sizes; (void)n_in; (void)out_size; (void)ws_size;
  const float* inputs_main = (const float*)d_in[0];
  const float* inputs_aux  = (const float*)d_in[1];
  const float* rnn1_mem    = (const float*)d_in[2];
  const float* Wi   = (const float*)d_in[3];
  const float* bi   = (const float*)d_in[4];
  const float* Ws1  = (const float*)d_in[5];
  const float* bs1  = (const float*)d_in[6];
  const float* Ws2  = (const float*)d_in[7];
  const float* bs2  = (const float*)d_in[8];
  const float* Wt1  = (const float*)d_in[9];
  const float* bt1  = (const float*)d_in[10];
  const float* Wt2  = (const float*)d_in[11];
  const float* bt2  = (const float*)d_in[12];
  const float* Wih1 = (const float*)d_in[13];
  const float* Whh1 = (const float*)d_in[14];
  const float* bih1 = (const float*)d_in[15];
  const float* bhh1 = (const float*)d_in[16];
  const float* Wih2 = (const float*)d_in[17];
  const float* Whh2 = (const float*)d_in[18];
  const float* bih2 = (const float*)d_in[19];
  const float* bhh2 = (const float*)d_in[20];
  const float* Wl   = (const float*)d_in[21];
  const float* bl   = (const float*)d_in[22];
  const float* Wo   = (const float*)d_in[23];
  const float* bo   = (const float*)d_in[24];
  const float* Wso  = (const float*)d_in[25];
  const float* bso  = (const float*)d_in[26];

  float* out     = (float*)d_out;
  float* out_sfc = out + (size_t)BATCH * NLAY * 4;
  float* new_mem = out_sfc + (size_t)BATCH * 3;

  ushort_t* frag  = (ushort_t*)d_ws;                          // 76800 ushorts
  ushort_t* r1buf = (ushort_t*)((char*)d_ws + 153600);        // [block][60][16][64] bf16
                                                              // (x prestage, then r1)

  wtranspose<<<300, 256, 0, stream>>>(Wih1, Whh1, Wih2, Whh2, Wl, Wo, Wso, frag);
  lstm_fused<<<BATCH / ROWS, TPB, 0, stream>>>(
      inputs_main, inputs_aux, rnn1_mem, Wi, bi, Ws1, bs1, Ws2, bs2,
      Wt1, bt1, Wt2, bt2, bih1, bhh1, bih2, bhh2, bl, Wo, bo, bso,
      frag, r1buf, out, out_sfc, new_mem);
}

// Round 10
// 258.202 us; speedup vs baseline: 1.1363x; 1.0322x over previous
//
#include <hip/hip_runtime.h>
#include <hip/hip_bf16.h>

#define BATCH 8192
#define NLAY  60
#define ROWS  16
#define TPB   256
#define SX    136     // xh row stride (ushort)
#define SM    968     // memAll row stride (ushort)
#define SI    244     // inm row stride (float)
#define LOG2E 1.44269504089f
#define T2L   2.88539008178f

typedef unsigned short ushort_t;
typedef __attribute__((ext_vector_type(8))) short short8;
typedef __attribute__((ext_vector_type(4))) float f32x4;
typedef __attribute__((ext_vector_type(4))) float f4v;

__device__ __forceinline__ float rcp_(float x) { return __builtin_amdgcn_rcpf(x); }
__device__ __forceinline__ float ex2_(float x) { return __builtin_amdgcn_exp2f(x); }
__device__ __forceinline__ ushort_t f2bu(float f) {
  unsigned u = __float_as_uint(f);
  return (ushort_t)((u + 0x7FFFu + ((u >> 16) & 1u)) >> 16);
}
__device__ __forceinline__ unsigned pkbf(float a, float b) {
  union { __hip_bfloat162 h; unsigned u; } c;
  c.h = __float22bfloat162_rn(make_float2(a, b));
  return c.u;
}
__device__ __forceinline__ f32x4 mfma16(short8 a, short8 b, f32x4 c) {
  return __builtin_amdgcn_mfma_f32_16x16x32_bf16(a, b, c, 0, 0, 0);
}
// LDS-only barrier: __syncthreads() drains vmcnt(0) too, which serializes the
// per-group r1/proj global stores into EVERY step. Only LDS ordering is needed
// for the h-exchange; global stores are fire-and-forget until the
// LSTM1->LSTM2 transition (full __syncthreads there).
#define BAR() asm volatile("s_waitcnt lgkmcnt(0)\n\ts_barrier" ::: "memory")

// ---- Pre-pass: pack weights into MFMA B-fragment order (bf16 bits) ----
// LSTM1 K-order: [x 0..63 | h 64..127 | mem 128..143 | pad 144..159]
// Gate weights PRE-SCALED: i,f,o by log2e ; g by 2*log2e (exp2-domain epilogue).
// W1f [w][g][ks5][512] @0 ; W2f [w][g][ks4][512] @40960 ; WlF @73728 ;
// WcF (Wo@Wl) @74752 ; WsF (Wso) @75776. Total 76800 ushorts.
__global__ void wtranspose(const float* __restrict__ Wih1, const float* __restrict__ Whh1,
                           const float* __restrict__ Wih2, const float* __restrict__ Whh2,
                           const float* __restrict__ Wl,   const float* __restrict__ Wo,
                           const float* __restrict__ Wso,  ushort_t* __restrict__ frag) {
  int e = blockIdx.x * 256 + threadIdx.x;
  float v;
  if (e < 40960) {
    int j = e & 7, lx = (e >> 3) & 63, rest = e >> 9;
    int ks = rest % 5, gw = rest / 5;
    int g = gw & 3, wv = gw >> 2;
    int row = g * 64 + wv * 16 + (lx & 15);
    int k = ks * 32 + (lx >> 4) * 8 + j;
    v = (k < 64)  ? Wih1[row * 80 + k]
      : (k < 128) ? Whh1[row * 64 + (k - 64)]
      : (k < 144) ? Wih1[row * 80 + 64 + (k - 128)]
      : 0.0f;
    v *= (g == 2) ? T2L : LOG2E;
  } else if (e < 73728) {
    int e2 = e - 40960;
    int j = e2 & 7, lx = (e2 >> 3) & 63, rest = e2 >> 9;
    int ks = rest & 3, g = (rest >> 2) & 3, wv = rest >> 4;
    int row = g * 64 + wv * 16 + (lx & 15);
    int k = ks * 32 + (lx >> 4) * 8 + j;
    v = (k < 64) ? Wih2[row * 64 + k] : Whh2[row * 64 + (k - 64)];
    v *= (g == 2) ? T2L : LOG2E;
  } else if (e < 74752) {
    int e3 = e - 73728;
    int j = e3 & 7, lx = (e3 >> 3) & 63, ks = e3 >> 9;
    int n = lx & 15, k = ks * 32 + (lx >> 4) * 8 + j;
    v = Wl[n * 64 + k];
  } else if (e < 75776) {
    int e4 = e - 74752;
    int j = e4 & 7, lx = (e4 >> 3) & 63, ks = e4 >> 9;
    int n = lx & 15, k = ks * 32 + (lx >> 4) * 8 + j;
    v = 0.0f;
    if (n < 4) {
#pragma unroll
      for (int m = 0; m < 16; ++m) v += Wo[n * 16 + m] * Wl[m * 64 + k];
    }
  } else {
    int e5 = e - 75776;
    int j = e5 & 7, lx = (e5 >> 3) & 63, ks = e5 >> 9;
    int n = lx & 15, k = ks * 32 + (lx >> 4) * 8 + j;
    v = (n < 3) ? Wso[n * 64 + k] : 0.0f;
  }
  frag[e] = f2bu(v);
}

// ---- Fused LSTM: 512 blocks x 256 thr, 16 rows/block, 2 blocks/CU.
// Measured optimum of the explored space (rounds 0-9):
//  - occupancy axis closed: 4 blocks/CU -> spills (r1); 3x8-rows -> zero-pad
//    MFMA tax (r2-3); 1 block ILP -> latency-exposed (r5).
//  - x-provisioning axis closed: recompute-in-loop 13.5us (this kernel) beats
//    fused-prologue 21us (r9) and separate-kernel 31us (r7-8) — the loop is
//    issue/stall-bound with idle slots, recompute rides them for free.
// Delta vs round 4 (253.9us verified): vectorized memAll staging only. ----
__global__ __launch_bounds__(TPB, 2)
void lstm_fused(const float* __restrict__ inputs_main, const float* __restrict__ inputs_aux,
                const float* __restrict__ rnn1_mem,
                const float* __restrict__ Wi,  const float* __restrict__ bi,
                const float* __restrict__ Ws1, const float* __restrict__ bs1,
                const float* __restrict__ Ws2, const float* __restrict__ bs2,
                const float* __restrict__ Wt1, const float* __restrict__ bt1,
                const float* __restrict__ Wt2, const float* __restrict__ bt2,
                const float* __restrict__ bih1, const float* __restrict__ bhh1,
                const float* __restrict__ bih2, const float* __restrict__ bhh2,
                const float* __restrict__ bl,  const float* __restrict__ Wo,
                const float* __restrict__ bo,  const float* __restrict__ bso,
                const ushort_t* __restrict__ frag,
                ushort_t* __restrict__ r1buf,
                float* __restrict__ out, float* __restrict__ out_sfc,
                float* __restrict__ new_mem) {
  const ushort_t* W1f = frag;
  const ushort_t* W2f = frag + 40960;
  const ushort_t* WlF = frag + 73728;
  const ushort_t* WcF = frag + 74752;
  const ushort_t* WsF = frag + 75776;

  __shared__ __align__(16) ushort_t xh[2][16 * SX];   // LSTM1: x|h1 ; LSTM2: r1|h2
  __shared__ __align__(16) ushort_t memAll[16 * SM];  // [row][t*16+m] bf16
  __shared__ __align__(16) float    inm[16 * SI];     // [row][t*4+c] fp32

  const int tid = threadIdx.x;
  const int lane = tid & 63, w = tid >> 6;
  const int ln = lane & 15, lq = lane >> 4;
  const int u = w * 16 + ln;
  const int rowbase = lq * 4;
  const int b0 = blockIdx.x * ROWS;
  const int xr = tid >> 4, xm = tid & 15, xc0 = xm * 4;
  const int rr8 = tid >> 3, ch8 = tid & 7;

  ushort_t* r1blk = r1buf + (size_t)blockIdx.x * (60 * 16 * 64);

  // B1 fragments (prescaled weights)
  short8 B1f[4][5];
#pragma unroll
  for (int g = 0; g < 4; ++g)
#pragma unroll
    for (int ks = 0; ks < 5; ++ks)
      B1f[g][ks] = *(const short8*)(W1f + (((w * 4 + g) * 5 + ks) << 9) + (lane << 3));
  float bg1[4];
#pragma unroll
  for (int g = 0; g < 4; ++g)
    bg1[g] = (bih1[g * 64 + u] + bhh1[g * 64 + u]) * ((g == 2) ? T2L : LOG2E);

  // x-generator weights, prescaled by 2*log2e
  f4v wif[4];
#pragma unroll
  for (int cc = 0; cc < 4; ++cc) wif[cc] = *(const f4v*)(Wi + (xc0 + cc) * 4) * T2L;
  f4v bifv = *(const f4v*)(bi + xc0) * T2L;

  // ---- stage static inputs (memAll vectorized: f4v load + pkbf pack) ----
  for (int e = tid; e < 16 * 240; e += TPB) {
    int r = e / 240, c = e - r * 240;
    inm[r * SI + c] = inputs_main[(size_t)(b0 + r) * 240 + c];
  }
  for (int e = tid; e < 16 * 240; e += TPB) {
    int r = e / 240, c = e - r * 240;
    f4v mv = *(const f4v*)(rnn1_mem + (size_t)(b0 + r) * 960 + c * 4);
    *(uint2*)&memAll[r * SM + c * 4] = make_uint2(pkbf(mv[0], mv[1]), pkbf(mv[2], mv[3]));
  }
  __syncthreads();

  // ---- prologue: x(59) + h1/c1 init into buffer 0 ----
  float ct1[4];   // cell state in 2*log2e-scaled domain
  {
    f4v xin = *(const f4v*)&inm[xr * SI + 59 * 4];
    float xp[4];
#pragma unroll
    for (int cc = 0; cc < 4; ++cc) {
      float a = fmaf(wif[cc][3], xin[3], fmaf(wif[cc][2], xin[2],
                fmaf(wif[cc][1], xin[1], fmaf(wif[cc][0], xin[0], bifv[cc]))));
      xp[cc] = fmaf(rcp_(1.0f + ex2_(a)), -2.0f, 1.0f);
    }
    *(uint2*)&xh[0][xr * SX + xc0] = make_uint2(pkbf(xp[0], xp[1]), pkbf(xp[2], xp[3]));

    float w10 = Ws1[u * 3 + 0] * T2L, w11 = Ws1[u * 3 + 1] * T2L, w12 = Ws1[u * 3 + 2] * T2L;
    float bb1 = bs1[u] * T2L;
    float w20 = Ws2[u * 3 + 0] * T2L, w21 = Ws2[u * 3 + 1] * T2L, w22 = Ws2[u * 3 + 2] * T2L;
    float bb2 = bs2[u] * T2L;
#pragma unroll
    for (int reg = 0; reg < 4; ++reg) {
      int row = rowbase + reg;
      const float* ax = inputs_aux + (size_t)(b0 + row) * 3;
      float a0 = ax[0], a1 = ax[1], a2 = ax[2];
      float ha = w10 * a0 + w11 * a1 + w12 * a2 + bb1;
      xh[0][row * SX + 64 + u] = f2bu(fmaf(rcp_(1.0f + ex2_(ha)), -2.0f, 1.0f));
      float ca = w20 * a0 + w21 * a1 + w22 * a2 + bb2;
      ct1[reg] = fmaf(rcp_(1.0f + ex2_(ca)), -2.0f * T2L, T2L);
    }
  }
  __syncthreads();

  ushort_t* r1t = r1blk + rowbase * 64 + u;
  unsigned sxv[4], syv[4];
  int pb = 0;

  // ---- LSTM1: t = 59..0 in groups of 4; r1 flushed once per group ----
  for (int tg = 14; tg >= 0; --tg) {
#pragma unroll
    for (int s = 3; s >= 0; --s) {
      const int t = tg * 4 + s;
      const int nb = pb ^ 1;
      const ushort_t* xrow = &xh[pb][ln * SX];
      short8 af0 = *(const short8*)(xrow + lq * 8);
      short8 af1 = *(const short8*)(xrow + 32 + lq * 8);
      short8 af2 = *(const short8*)(xrow + 64 + lq * 8);
      short8 af3 = *(const short8*)(xrow + 96 + lq * 8);
      short8 af4 = {};
      if (lq < 2) af4 = *(const short8*)(memAll + ln * SM + t * 16 + lq * 8);

      f32x4 acc[4];
#pragma unroll
      for (int g = 0; g < 4; ++g) acc[g] = (f32x4){bg1[g], bg1[g], bg1[g], bg1[g]};
      __builtin_amdgcn_s_setprio(1);
#pragma unroll
      for (int g = 0; g < 4; ++g) {
        acc[g] = mfma16(af0, B1f[g][0], acc[g]);
        acc[g] = mfma16(af1, B1f[g][1], acc[g]);
        acc[g] = mfma16(af2, B1f[g][2], acc[g]);
        acc[g] = mfma16(af3, B1f[g][3], acc[g]);
        acc[g] = mfma16(af4, B1f[g][4], acc[g]);
      }
      __builtin_amdgcn_s_setprio(0);

      if (t > 0) {  // x(t-1) into next buffer
        f4v xin = *(const f4v*)&inm[xr * SI + (t - 1) * 4];
        float xp[4];
#pragma unroll
        for (int cc = 0; cc < 4; ++cc) {
          float a = fmaf(wif[cc][3], xin[3], fmaf(wif[cc][2], xin[2],
                    fmaf(wif[cc][1], xin[1], fmaf(wif[cc][0], xin[0], bifv[cc]))));
          xp[cc] = fmaf(rcp_(1.0f + ex2_(a)), -2.0f, 1.0f);
        }
        *(uint2*)&xh[nb][xr * SX + xc0] = make_uint2(pkbf(xp[0], xp[1]), pkbf(xp[2], xp[3]));
      }

      float h[4];
#pragma unroll
      for (int reg = 0; reg < 4; ++reg) {
        float si = rcp_(1.0f + ex2_(-acc[0][reg]));
        float sf = rcp_(1.0f + ex2_(-acc[1][reg]));
        float so = rcp_(1.0f + ex2_(-acc[3][reg]));
        float gt = fmaf(rcp_(1.0f + ex2_(acc[2][reg])), -2.0f * T2L, T2L);
        ct1[reg] = fmaf(sf, ct1[reg], si * gt);
        float tc = fmaf(rcp_(1.0f + ex2_(ct1[reg])), -2.0f, 1.0f);
        h[reg] = so * tc;
      }
      unsigned h01 = pkbf(h[0], h[1]), h23 = pkbf(h[2], h[3]);
      sxv[s] = h01; syv[s] = h23;              // stash; flush after the group
      if (t > 0) {
        xh[nb][(rowbase + 0) * SX + 64 + u] = (ushort_t)h01;
        xh[nb][(rowbase + 1) * SX + 64 + u] = (ushort_t)(h01 >> 16);
        xh[nb][(rowbase + 2) * SX + 64 + u] = (ushort_t)h23;
        xh[nb][(rowbase + 3) * SX + 64 + u] = (ushort_t)(h23 >> 16);
      } else {                                  // r1(0) seeds LSTM2 input region
        xh[nb][(rowbase + 0) * SX + u] = (ushort_t)h01;
        xh[nb][(rowbase + 1) * SX + u] = (ushort_t)(h01 >> 16);
        xh[nb][(rowbase + 2) * SX + u] = (ushort_t)h23;
        xh[nb][(rowbase + 3) * SX + u] = (ushort_t)(h23 >> 16);
      }
      BAR();
      pb = nb;
    }
    // flush r1 for tt = tg*4 .. tg*4+3 (retires in background; no barrier drain)
    ushort_t* rp = r1t + (tg << 12);
#pragma unroll
    for (int s = 0; s < 4; ++s) {
      unsigned a = sxv[s], b = syv[s];
      rp[s * 1024 + 0 * 64] = (ushort_t)a;
      rp[s * 1024 + 1 * 64] = (ushort_t)(a >> 16);
      rp[s * 1024 + 2 * 64] = (ushort_t)b;
      rp[s * 1024 + 3 * 64] = (ushort_t)(b >> 16);
    }
  }

  // ---- LSTM2 setup ----
  short8 B2f[4][4];
#pragma unroll
  for (int g = 0; g < 4; ++g)
#pragma unroll
    for (int ks = 0; ks < 4; ++ks)
      B2f[g][ks] = *(const short8*)(W2f + (((w * 4 + g) * 4 + ks) << 9) + (lane << 3));
  float bg2[4];
#pragma unroll
  for (int g = 0; g < 4; ++g)
    bg2[g] = (bih2[g * 64 + u] + bhh2[g * 64 + u]) * ((g == 2) ? T2L : LOG2E);

  float ct2[4];
  {
    float wt1u = Wt1[u], wt2u = Wt2[u], bt1u = bt1[u], bt2u = bt2[u];
#pragma unroll
    for (int reg = 0; reg < 4; ++reg) {
      int row = rowbase + reg;
      float toa = inputs_aux[(size_t)(b0 + row) * 3 + 1];
      xh[pb][row * SX + 64 + u] = f2bu(toa * wt1u + bt1u);   // no tanh (ref)
      ct2[reg] = (toa * wt2u + bt2u) * T2L;
    }
  }
  short8 PW0 = {}, PW1 = {};
  float pbias = 0.0f;
  if (w == 0) {
    PW0 = *(const short8*)(WlF + (lane << 3));
    PW1 = *(const short8*)(WlF + 512 + (lane << 3));
    pbias = bl[ln];
  } else if (w == 1) {
    PW0 = *(const short8*)(WcF + (lane << 3));
    PW1 = *(const short8*)(WcF + 512 + (lane << 3));
    if (ln < 4) {
      float a = bo[ln];
#pragma unroll
      for (int m = 0; m < 16; ++m) a += Wo[ln * 16 + m] * bl[m];
      pbias = a;
    }
  } else if (w == 2) {
    PW0 = *(const short8*)(WsF + (lane << 3));
    PW1 = *(const short8*)(WsF + 512 + (lane << 3));
    pbias = (ln < 3) ? bso[ln] : 0.0f;
  }
  const ushort_t* r1rp = r1blk + 1024 + rr8 * 64 + ch8 * 8;
  float* nmb = new_mem + (size_t)(b0 + rowbase) * 960 + ln;
  float* outb = out + (size_t)(b0 + rowbase) * 240 + ln;
  f32x4 pst[4];
  __syncthreads();   // FULL barrier: drains r1 global writes before re-reads

  // ---- LSTM2: t = 0..59 in groups of 4; proj stores flushed per group ----
  for (int tg = 0; tg < 15; ++tg) {
#pragma unroll
    for (int s = 0; s < 4; ++s) {
      const int t = tg * 4 + s;
      const int nb = pb ^ 1;
      short8 r1v = {};
      if (t < 59 && tid < 128) r1v = *(const short8*)(r1rp + t * 1024);

      const ushort_t* xrow = &xh[pb][ln * SX];
      short8 af0 = *(const short8*)(xrow + lq * 8);
      short8 af1 = *(const short8*)(xrow + 32 + lq * 8);
      short8 af2 = *(const short8*)(xrow + 64 + lq * 8);
      short8 af3 = *(const short8*)(xrow + 96 + lq * 8);

      f32x4 acc[4];
#pragma unroll
      for (int g = 0; g < 4; ++g) acc[g] = (f32x4){bg2[g], bg2[g], bg2[g], bg2[g]};
      __builtin_amdgcn_s_setprio(1);
#pragma unroll
      for (int g = 0; g < 4; ++g) {
        acc[g] = mfma16(af0, B2f[g][0], acc[g]);
        acc[g] = mfma16(af1, B2f[g][1], acc[g]);
        acc[g] = mfma16(af2, B2f[g][2], acc[g]);
        acc[g] = mfma16(af3, B2f[g][3], acc[g]);
      }

      if (t > 0 && w < 2) {  // projection of h2(t-1) — reuses af2/af3
        f32x4 ap = (f32x4){pbias, pbias, pbias, pbias};
        ap = mfma16(af2, PW0, ap);
        ap = mfma16(af3, PW1, ap);
        pst[(t - 1) & 3] = ap;
      }
      __builtin_amdgcn_s_setprio(0);

      float h[4];
#pragma unroll
      for (int reg = 0; reg < 4; ++reg) {
        float si = rcp_(1.0f + ex2_(-acc[0][reg]));
        float sf = rcp_(1.0f + ex2_(-acc[1][reg]));
        float so = rcp_(1.0f + ex2_(-acc[3][reg]));
        float gt = fmaf(rcp_(1.0f + ex2_(acc[2][reg])), -2.0f * T2L, T2L);
        ct2[reg] = fmaf(sf, ct2[reg], si * gt);
        float tc = fmaf(rcp_(1.0f + ex2_(ct2[reg])), -2.0f, 1.0f);
        h[reg] = so * tc;
      }
      unsigned h01 = pkbf(h[0], h[1]), h23 = pkbf(h[2], h[3]);
      xh[nb][(rowbase + 0) * SX + 64 + u] = (ushort_t)h01;
      xh[nb][(rowbase + 1) * SX + 64 + u] = (ushort_t)(h01 >> 16);
      xh[nb][(rowbase + 2) * SX + 64 + u] = (ushort_t)h23;
      xh[nb][(rowbase + 3) * SX + 64 + u] = (ushort_t)(h23 >> 16);
      if (t < 59 && tid < 128)
        *(short8*)&xh[nb][rr8 * SX + ch8 * 8] = r1v;
      BAR();
      pb = nb;
    }
    // flush projections: slots 0,1,2 -> pt = tg*4+{0,1,2}; slot 3 -> pt = tg*4-1
    if (w < 2) {
      const int base = tg * 4;
#pragma unroll
      for (int k = 0; k < 4; ++k) {
        const int pt = (k == 3) ? base - 1 : base + k;
        if (pt < 0) continue;
        f32x4 ap = pst[k];
        if (w == 0) {
#pragma unroll
          for (int reg = 0; reg < 4; ++reg) nmb[reg * 960 + pt * 16] = ap[reg];
        } else if (ln < 4) {
#pragma unroll
          for (int reg = 0; reg < 4; ++reg) outb[reg * 240 + pt * 4] = ap[reg];
        }
      }
    }
  }

  // ---- tail: pt = 59 projections + out_sfc from final h2 (xh[pb]) ----
  if (w < 3) {
    const ushort_t* xrow = &xh[pb][ln * SX];
    short8 aL0 = *(const short8*)(xrow + 64 + lq * 8);
    short8 aL1 = *(const short8*)(xrow + 96 + lq * 8);
    f32x4 ap = (f32x4){pbias, pbias, pbias, pbias};
    ap = mfma16(aL0, PW0, ap);
    ap = mfma16(aL1, PW1, ap);
    if (w == 0) {
#pragma unroll
      for (int reg = 0; reg < 4; ++reg) nmb[reg * 960 + 59 * 16] = ap[reg];
    } else if (w == 1) {
      if (ln < 4) {
#pragma unroll
        for (int reg = 0; reg < 4; ++reg) outb[reg * 240 + 59 * 4] = ap[reg];
      }
    } else {
      if (ln < 3) {
#pragma unroll
        for (int reg = 0; reg < 4; ++reg)
          out_sfc[(size_t)(b0 + rowbase + reg) * 3 + ln] = ap[reg];
      }
    }
  }
}

extern "C" void kernel_launch(void* const* d_in, const int* in_sizes, int n_in,
                              void* d_out, int out_size, void* d_ws, size_t ws_size,
                              hipStream_t stream) {
  (void)in_sizes; (void)n_in; (void)out_size; (void)ws_size;
  const float* inputs_main = (const float*)d_in[0];
  const float* inputs_aux  = (const float*)d_in[1];
  const float* rnn1_mem    = (const float*)d_in[2];
  const float* Wi   = (const float*)d_in[3];
  const float* bi   = (const float*)d_in[4];
  const float* Ws1  = (const float*)d_in[5];
  const float* bs1  = (const float*)d_in[6];
  const float* Ws2  = (const float*)d_in[7];
  const float* bs2  = (const float*)d_in[8];
  const float* Wt1  = (const float*)d_in[9];
  const float* bt1  = (const float*)d_in[10];
  const float* Wt2  = (const float*)d_in[11];
  const float* bt2  = (const float*)d_in[12];
  const float* Wih1 = (const float*)d_in[13];
  const float* Whh1 = (const float*)d_in[14];
  const float* bih1 = (const float*)d_in[15];
  const float* bhh1 = (const float*)d_in[16];
  const float* Wih2 = (const float*)d_in[17];
  const float* Whh2 = (const float*)d_in[18];
  const float* bih2 = (const float*)d_in[19];
  const float* bhh2 = (const float*)d_in[20];
  const float* Wl   = (const float*)d_in[21];
  const float* bl   = (const float*)d_in[22];
  const float* Wo   = (const float*)d_in[23];
  const float* bo   = (const float*)d_in[24];
  const float* Wso  = (const float*)d_in[25];
  const float* bso  = (const float*)d_in[26];

  float* out     = (float*)d_out;
  float* out_sfc = out + (size_t)BATCH * NLAY * 4;
  float* new_mem = out_sfc + (size_t)BATCH * 3;

  ushort_t* frag  = (ushort_t*)d_ws;                          // 76800 ushorts
  ushort_t* r1buf = (ushort_t*)((char*)d_ws + 153600);        // [block][60][16][64] bf16

  wtranspose<<<300, 256, 0, stream>>>(Wih1, Whh1, Wih2, Whh2, Wl, Wo, Wso, frag);
  lstm_fused<<<BATCH / ROWS, TPB, 0, stream>>>(
      inputs_main, inputs_aux, rnn1_mem, Wi, bi, Ws1, bs1, Ws2, bs2,
      Wt1, bt1, Wt2, bt2, bih1, bhh1, bih2, bhh2, bl, Wo, bo, bso,
      frag, r1buf, out, out_sfc, new_mem);
}